// Round 10
// baseline (399.321 us; speedup 1.0000x reference)
//
#include <hip/hip_runtime.h>

#define NS 4096
#define NT 8192
#define DIN 256
#define DOUT 128

// float offsets into workspace
#define OFF_RS   0                       // deg_s then rs in place [NS]
#define OFF_RT   (NS)                    // deg_t then rt in place [NT]
#define OFF_C1   (OFF_RT + NT)
#define OFF_C2   (OFF_C1 + NS*DOUT)
#define OFF_XS   (OFF_C2 + NT*DOUT)
#define OFF_YS   (OFF_XS + NS*DOUT)
#define OFF_XNS  (OFF_YS + NT*DOUT)
#define OFF_XST  (OFF_XNS + NS*DOUT)               // bf16 [128][NS]
#define OFF_YST  (OFF_XST + (128*NS)/2)            // bf16 [128][NT]
#define OFF_ABF  (OFF_YST + (128*NT)/2)            // bf16 adj   [NS][NT]
#define OFF_SBF  (OFF_ABF + (NS*NT)/2)             // bf16 adj_s [NS][NS]
#define OFF_TBF  (OFF_SBF + (NS*NS)/2)             // bf16 adj_t [NT][NT]

typedef __attribute__((ext_vector_type(8))) short bf8v;
typedef __attribute__((ext_vector_type(4))) float f32x4;
typedef __attribute__((ext_vector_type(4))) unsigned short u16x4;

__device__ __forceinline__ ushort f2bf(float f) {
    // exact round-to-nearest-even fp32 -> bf16 (finite inputs only)
    unsigned x = __float_as_uint(f);
    unsigned r = (x + 0x7fffu + ((x >> 16) & 1u)) >> 16;
    return (ushort)r;
}

__device__ __forceinline__ u16x4 f2bf4(float4 v) {
    u16x4 w;
    w[0] = f2bf(v.x); w[1] = f2bf(v.y); w[2] = f2bf(v.z); w[3] = f2bf(v.w);
    return w;
}

__global__ void zero_kernel(float* __restrict__ p, int n4) {
    int i = blockIdx.x * blockDim.x + threadIdx.x;
    int stride = gridDim.x * blockDim.x;
    float4* p4 = (float4*)p;
    float4 z = make_float4(0.f, 0.f, 0.f, 0.f);
    for (; i < n4; i += stride) p4[i] = z;
}

// One pass over adj: row partials -> deg_s, col partials -> deg_t, bf16 copy out
__global__ __launch_bounds__(256)
void adj_deg_kernel(const float* __restrict__ adj,
                    float* __restrict__ deg_s, float* __restrict__ deg_t,
                    ushort* __restrict__ adjb) {
    const int tid = threadIdx.x;
    const int lane = tid & 63;
    const int c4 = blockIdx.x * 256 + tid;          // float4 column
    const int r0 = blockIdx.y * 32;
    const float4* A4 = (const float4*)adj + (size_t)r0 * (NT / 4) + c4;
    float sx = 0.f, sy = 0.f, sz = 0.f, sw = 0.f;
#pragma unroll 8
    for (int r = 0; r < 32; ++r) {
        float4 v = A4[(size_t)r * (NT / 4)];
        *(u16x4*)&adjb[(size_t)(r0 + r) * NT + c4 * 4] = f2bf4(v);
        sx += v.x; sy += v.y; sz += v.z; sw += v.w;
        float rp = v.x + v.y + v.z + v.w;
#pragma unroll
        for (int off = 32; off > 0; off >>= 1) rp += __shfl_down(rp, off, 64);
        if (lane == 0) unsafeAtomicAdd(deg_s + r0 + r, rp);
    }
    float* d = deg_t + c4 * 4;
    unsafeAtomicAdd(d + 0, sx);
    unsafeAtomicAdd(d + 1, sy);
    unsafeAtomicAdd(d + 2, sz);
    unsafeAtomicAdd(d + 3, sw);
}

// adj_s row sums -> deg_s, bf16 copy out; one wave per row
__global__ __launch_bounds__(256)
void rowsum_s_kernel(const float* __restrict__ adj_s, float* __restrict__ deg_s,
                     ushort* __restrict__ outb) {
    const int wid = threadIdx.x >> 6;
    const int lane = threadIdx.x & 63;
    const int row = blockIdx.x * 4 + wid;
    const float4* b = (const float4*)(adj_s + (size_t)row * NS);
    float sum = 0.f;
#pragma unroll 8
    for (int c = lane; c < NS / 4; c += 64) {
        float4 v = b[c];
        *(u16x4*)&outb[(size_t)row * NS + c * 4] = f2bf4(v);
        sum += v.x + v.y + v.z + v.w;
    }
#pragma unroll
    for (int off = 32; off > 0; off >>= 1) sum += __shfl_down(sum, off, 64);
    if (lane == 0) unsafeAtomicAdd(deg_s + row, sum);
}

// adj_t col partial sums -> deg_t, bf16 copy out
__global__ __launch_bounds__(256)
void colsum_t_kernel(const float* __restrict__ A, float* __restrict__ deg_t,
                     ushort* __restrict__ outb) {
    const int c4 = blockIdx.x * 256 + threadIdx.x;
    const int r0 = blockIdx.y * 64;
    const float4* A4 = (const float4*)A + (size_t)r0 * (NT / 4) + c4;
    float sx = 0.f, sy = 0.f, sz = 0.f, sw = 0.f;
#pragma unroll 8
    for (int r = 0; r < 64; ++r) {
        float4 v = A4[(size_t)r * (NT / 4)];
        *(u16x4*)&outb[(size_t)(r0 + r) * NT + c4 * 4] = f2bf4(v);
        sx += v.x; sy += v.y; sz += v.z; sw += v.w;
    }
    float* d = deg_t + c4 * 4;
    unsafeAtomicAdd(d + 0, sx);
    unsafeAtomicAdd(d + 1, sy);
    unsafeAtomicAdd(d + 2, sz);
    unsafeAtomicAdd(d + 3, sw);
}

// deg -> sqrt(deg + 1), in place over rs|rt (contiguous NS+NT)
__global__ void finish_deg_kernel(float* __restrict__ deg) {
    int t = blockIdx.x * blockDim.x + threadIdx.x;
    deg[t] = sqrtf(deg[t] + 1.0f);
}

// out[m,:] = (inp[m,:] @ W) / rdeg[m]  (fp32), plus outT[n][m] = bf16(out[m][n])
__global__ __launch_bounds__(256)
void proj_scale_kernel(const float* __restrict__ inp,
                       const float* __restrict__ W,
                       const float* __restrict__ rdeg,
                       float* __restrict__ outp,
                       ushort* __restrict__ outT, int M) {
    __shared__ float As[32][68];
    __shared__ float Bs[32][128];
    const int tid = threadIdx.x;
    const int m0 = blockIdx.x * 64;
    const int tx = tid & 15, ty = tid >> 4;
    const int arow = tid >> 3, acg = tid & 7;
    const int bk = tid >> 5, bng = tid & 31;

    float acc[4][8];
#pragma unroll
    for (int r = 0; r < 4; ++r)
#pragma unroll
        for (int c = 0; c < 8; ++c) acc[r][c] = 0.f;

    for (int kt = 0; kt < DIN; kt += 32) {
        const float* Ab = inp + (size_t)(m0 + arow) * DIN + kt + acg * 4;
        float4 a0 = *(const float4*)Ab;
        float4 a1 = *(const float4*)(Ab + (size_t)32 * DIN);
        const float* Bb = W + (size_t)(kt + bk) * DOUT + bng * 4;
        float4 b0 = *(const float4*)Bb;
        float4 b1 = *(const float4*)(Bb + 8 * DOUT);
        float4 b2 = *(const float4*)(Bb + 16 * DOUT);
        float4 b3 = *(const float4*)(Bb + 24 * DOUT);
        __syncthreads();
        As[acg * 4 + 0][arow] = a0.x;
        As[acg * 4 + 1][arow] = a0.y;
        As[acg * 4 + 2][arow] = a0.z;
        As[acg * 4 + 3][arow] = a0.w;
        As[acg * 4 + 0][arow + 32] = a1.x;
        As[acg * 4 + 1][arow + 32] = a1.y;
        As[acg * 4 + 2][arow + 32] = a1.z;
        As[acg * 4 + 3][arow + 32] = a1.w;
        *(float4*)&Bs[bk][bng * 4] = b0;
        *(float4*)&Bs[bk + 8][bng * 4] = b1;
        *(float4*)&Bs[bk + 16][bng * 4] = b2;
        *(float4*)&Bs[bk + 24][bng * 4] = b3;
        __syncthreads();
#pragma unroll
        for (int k = 0; k < 32; ++k) {
            float4 av = *(const float4*)&As[k][ty * 4];
            float4 bv0 = *(const float4*)&Bs[k][tx * 4];
            float4 bv1 = *(const float4*)&Bs[k][tx * 4 + 64];
            float a[4] = {av.x, av.y, av.z, av.w};
            float b[8] = {bv0.x, bv0.y, bv0.z, bv0.w, bv1.x, bv1.y, bv1.z, bv1.w};
#pragma unroll
            for (int r = 0; r < 4; ++r)
#pragma unroll
                for (int c = 0; c < 8; ++c) acc[r][c] = fmaf(a[r], b[c], acc[r][c]);
        }
    }
    float rds[4];
#pragma unroll
    for (int r = 0; r < 4; ++r) rds[r] = rdeg[m0 + ty * 4 + r];
#pragma unroll
    for (int r = 0; r < 4; ++r) {
        int row = m0 + ty * 4 + r;
        float* orow = outp + (size_t)row * DOUT;
#pragma unroll
        for (int c = 0; c < 8; ++c) acc[r][c] /= rds[r];
#pragma unroll
        for (int c = 0; c < 4; ++c) {
            orow[tx * 4 + c] = acc[r][c];
            orow[tx * 4 + 64 + c] = acc[r][4 + c];
        }
    }
#pragma unroll
    for (int c = 0; c < 8; ++c) {
        int col = tx * 4 + (c & 3) + (c >> 2) * 64;
        u16x4 w;
#pragma unroll
        for (int r = 0; r < 4; ++r) w[r] = f2bf(acc[r][c]);
        *(u16x4*)&outT[(size_t)col * M + m0 + ty * 4] = w;
    }
}

// C[m0:m0+128, 0:128] += op(A)[m0:m0+128, k0:k0+kchunk] @ B[k0:k0+kchunk, 0:128]
// A is bf16. TRANS=0: A[m][k] pitch lda. TRANS=1: op(A)=A^T with A[k][m] pitch lda.
// BTF=1: B bf16 transposed bT[n][k] pitch ldb. BTF=0: B fp32 row-major [k][128].
template<int TRANS, int BTF>
__global__ __launch_bounds__(256)
void gemm_mfma_kernel(const ushort* __restrict__ A, int lda,
                      const float* __restrict__ Bf,
                      const ushort* __restrict__ bT, int ldb,
                      float* __restrict__ C, int kchunk) {
    __shared__ ushort As[128][40];   // [m][k], pitch 80 B
    __shared__ ushort Bs[128][40];   // [n][k]
    const int tid = threadIdx.x;
    const int m0 = blockIdx.x * 128;
    const int k0 = blockIdx.y * kchunk;
    const int lane = tid & 63, wid = tid >> 6;
    const int wm = (wid >> 1) * 64, wn = (wid & 1) * 64;
    const int r16 = lane & 15, kg = lane >> 4;

    const int s_kr = tid >> 3, s_f4 = tid & 7;   // fp32-B staging map
    const int a_r = tid >> 1, a_seg = tid & 1;   // NN-A bf16 staging map
    const int t2_kr = tid >> 3, t2_m = tid & 7;  // TRANS-A bf16 staging map
    const int t_n = tid >> 2, t_seg = tid & 3;   // bf16-T B staging map

    f32x4 acc[4][4];
#pragma unroll
    for (int i = 0; i < 4; ++i)
#pragma unroll
        for (int j = 0; j < 4; ++j) acc[i][j] = (f32x4)(0.f);

    bf8v aPT[2];
    float4 bP[4];
    bf8v bPT[2];

    auto loadB = [&](int ktb) {
        if (BTF) {
#pragma unroll
            for (int p = 0; p < 2; ++p)
                bPT[p] = *(const bf8v*)(bT + (size_t)(t_n + p * 64) * ldb + k0 + ktb + t_seg * 8);
        } else {
            const float* Bb = Bf + (size_t)(k0 + ktb + s_kr) * DOUT + s_f4 * 4;
#pragma unroll
            for (int i = 0; i < 4; ++i) bP[i] = *(const float4*)(Bb + i * 32);
        }
    };
    auto loadA = [&](int ktb) {
        if (TRANS) {
            const ushort* Ab = A + (size_t)(k0 + ktb + t2_kr) * lda + m0 + t2_m * 16;
            aPT[0] = *(const bf8v*)Ab;
            aPT[1] = *(const bf8v*)(Ab + 8);
        } else {
            const ushort* Ab = A + (size_t)(m0 + a_r) * lda + k0 + ktb + a_seg * 16;
            aPT[0] = *(const bf8v*)Ab;
            aPT[1] = *(const bf8v*)(Ab + 8);
        }
    };

    loadB(0); loadA(0);

    for (int kt = 0; kt < kchunk; kt += 32) {
        __syncthreads();
        if (TRANS) {
#pragma unroll
            for (int e = 0; e < 8; ++e) {
                As[t2_m * 16 + e][t2_kr] = (ushort)aPT[0][e];
                As[t2_m * 16 + 8 + e][t2_kr] = (ushort)aPT[1][e];
            }
        } else {
            *(bf8v*)&As[a_r][a_seg * 16] = aPT[0];
            *(bf8v*)&As[a_r][a_seg * 16 + 8] = aPT[1];
        }
        if (BTF) {
#pragma unroll
            for (int p = 0; p < 2; ++p)
                *(bf8v*)&Bs[t_n + p * 64][t_seg * 8] = bPT[p];
        } else {
#pragma unroll
            for (int i = 0; i < 4; ++i) {
                int n = s_f4 * 4 + i * 32;
                Bs[n + 0][s_kr] = f2bf(bP[i].x);
                Bs[n + 1][s_kr] = f2bf(bP[i].y);
                Bs[n + 2][s_kr] = f2bf(bP[i].z);
                Bs[n + 3][s_kr] = f2bf(bP[i].w);
            }
        }
        __syncthreads();

        if (kt + 32 < kchunk) { loadB(kt + 32); loadA(kt + 32); }

        bf8v af[4], bf[4];
#pragma unroll
        for (int f = 0; f < 4; ++f) af[f] = *(const bf8v*)&As[wm + f * 16 + r16][kg * 8];
#pragma unroll
        for (int f = 0; f < 4; ++f) bf[f] = *(const bf8v*)&Bs[wn + f * 16 + r16][kg * 8];
#pragma unroll
        for (int i = 0; i < 4; ++i)
#pragma unroll
            for (int j = 0; j < 4; ++j)
                acc[i][j] = __builtin_amdgcn_mfma_f32_16x16x32_bf16(af[i], bf[j], acc[i][j], 0, 0, 0);
    }

    const int crow0 = m0 + wm + (lane >> 4) * 4;
#pragma unroll
    for (int i = 0; i < 4; ++i) {
#pragma unroll
        for (int j = 0; j < 4; ++j) {
            float* base = C + (size_t)(crow0 + i * 16) * DOUT + wn + j * 16 + r16;
            unsafeAtomicAdd(base + 0 * DOUT, acc[i][j][0]);
            unsafeAtomicAdd(base + 1 * DOUT, acc[i][j][1]);
            unsafeAtomicAdd(base + 2 * DOUT, acc[i][j][2]);
            unsafeAtomicAdd(base + 3 * DOUT, acc[i][j][3]);
        }
    }
}

// x_new = relu(xs + C1/rs) -> d_out;  xns = x_new/rs -> ws (fp32)
__global__ void epilogue1_kernel(const float* __restrict__ C1,
                                 const float* __restrict__ xs,
                                 const float* __restrict__ rs,
                                 float* __restrict__ outx,
                                 float* __restrict__ xns) {
    int idx = blockIdx.x * blockDim.x + threadIdx.x;
    if (idx >= NS * DOUT) return;
    int row = idx >> 7;
    float r = rs[row];
    float v = xs[idx] + C1[idx] / r;
    v = v > 0.f ? v : 0.f;
    outx[idx] = v;
    xns[idx] = v / r;
}

// y_new = relu(ys + C2/rt) -> d_out + NS*DOUT
__global__ void epilogue2_kernel(const float* __restrict__ C2,
                                 const float* __restrict__ ys,
                                 const float* __restrict__ rt,
                                 float* __restrict__ outy) {
    int idx = blockIdx.x * blockDim.x + threadIdx.x;
    if (idx >= NT * DOUT) return;
    int row = idx >> 7;
    float v = ys[idx] + C2[idx] / rt[row];
    v = v > 0.f ? v : 0.f;
    outy[idx] = v;
}

extern "C" void kernel_launch(void* const* d_in, const int* in_sizes, int n_in,
                              void* d_out, int out_size, void* d_ws, size_t ws_size,
                              hipStream_t stream) {
    const float* inp_s = (const float*)d_in[0];
    const float* inp_t = (const float*)d_in[1];
    const float* adj   = (const float*)d_in[2];
    const float* adj_s = (const float*)d_in[3];
    const float* adj_t = (const float*)d_in[4];
    const float* W     = (const float*)d_in[5];
    float* out = (float*)d_out;
    float* ws  = (float*)d_ws;

    float* rs  = ws + OFF_RS;
    float* rt  = ws + OFF_RT;
    float* C1  = ws + OFF_C1;
    float* C2  = ws + OFF_C2;
    float* xs  = ws + OFF_XS;
    float* ys  = ws + OFF_YS;
    float* xns = ws + OFF_XNS;
    ushort* xsT = (ushort*)(ws + OFF_XST);
    ushort* ysT = (ushort*)(ws + OFF_YST);
    ushort* adj_bf   = (ushort*)(ws + OFF_ABF);
    ushort* adj_s_bf = (ushort*)(ws + OFF_SBF);
    ushort* adj_t_bf = (ushort*)(ws + OFF_TBF);

    // zero deg_s + deg_t + C1 + C2 (contiguous [0, OFF_XS))
    zero_kernel<<<1024, 256, 0, stream>>>(ws, OFF_XS / 4);

    // Degree pass (reads fp32 once, emits bf16 copies), ordered for LLC:
    // stream adj_t (268 MB) FIRST so adj/adj_s bf16 copies stay resident.
    colsum_t_kernel<<<dim3(NT / 1024, NT / 64), 256, 0, stream>>>(adj_t, rt, adj_t_bf);
    adj_deg_kernel<<<dim3(NT / 1024, NS / 32), 256, 0, stream>>>(adj, rs, rt, adj_bf);
    rowsum_s_kernel<<<NS / 4, 256, 0, stream>>>(adj_s, rs, adj_s_bf);
    finish_deg_kernel<<<(NS + NT) / 256, 256, 0, stream>>>(rs);   // rs|rt contiguous

    // projections: xs = (inp_s@W)/rs (fp32) + xsT (bf16 transposed); same for ys
    proj_scale_kernel<<<NS / 64, 256, 0, stream>>>(inp_s, W, rs, xs, xsT, NS);
    proj_scale_kernel<<<NT / 64, 256, 0, stream>>>(inp_t, W, rt, ys, ysT, NT);

    // GEMMs (all-bf16 A), LLC-warm first, adj_t (cold) last.
    // C1 = adj_s@xs + adj@ys   [NS,128]
    gemm_mfma_kernel<0, 1><<<dim3(NS / 128, 8), 256, 0, stream>>>(adj_s_bf, NS, nullptr, xsT, NS, C1, NS / 8);
    gemm_mfma_kernel<0, 1><<<dim3(NS / 128, 8), 256, 0, stream>>>(adj_bf, NT, nullptr, ysT, NT, C1, NT / 8);
    epilogue1_kernel<<<(NS * DOUT) / 256, 256, 0, stream>>>(C1, xs, rs, out, xns);

    // C2 = adj^T@xns + adj_t@ys   [NT,128]
    gemm_mfma_kernel<1, 0><<<dim3(NT / 128, 8), 256, 0, stream>>>(adj_bf, NT, xns, nullptr, 0, C2, NS / 8);
    gemm_mfma_kernel<0, 1><<<dim3(NT / 128, 8), 256, 0, stream>>>(adj_t_bf, NT, nullptr, ysT, NT, C2, NT / 8);
    epilogue2_kernel<<<(NT * DOUT) / 256, 256, 0, stream>>>(C2, ys, rt, out + NS * DOUT);
}

// Round 11
// 384.266 us; speedup vs baseline: 1.0392x; 1.0392x over previous
//
#include <hip/hip_runtime.h>

#define NS 4096
#define NT 8192
#define DIN 256
#define DOUT 128

// float offsets into workspace
#define OFF_RS   0                       // deg_s then rs in place [NS]
#define OFF_RT   (NS)                    // deg_t then rt in place [NT]
#define OFF_C1   (OFF_RT + NT)
#define OFF_C2   (OFF_C1 + NS*DOUT)
#define OFF_XS   (OFF_C2 + NT*DOUT)
#define OFF_YS   (OFF_XS + NS*DOUT)
#define OFF_XNS  (OFF_YS + NT*DOUT)
#define OFF_XST  (OFF_XNS + NS*DOUT)               // bf16 [128][NS]
#define OFF_YST  (OFF_XST + (128*NS)/2)            // bf16 [128][NT]

typedef __attribute__((ext_vector_type(8))) short bf8v;
typedef __attribute__((ext_vector_type(4))) float f32x4;
typedef __attribute__((ext_vector_type(4))) unsigned short u16x4;

__device__ __forceinline__ ushort f2bf(float f) {
    // exact round-to-nearest-even fp32 -> bf16 (finite inputs only)
    unsigned x = __float_as_uint(f);
    unsigned r = (x + 0x7fffu + ((x >> 16) & 1u)) >> 16;
    return (ushort)r;
}

__global__ void zero_kernel(float* __restrict__ p, int n4) {
    int i = blockIdx.x * blockDim.x + threadIdx.x;
    int stride = gridDim.x * blockDim.x;
    float4* p4 = (float4*)p;
    float4 z = make_float4(0.f, 0.f, 0.f, 0.f);
    for (; i < n4; i += stride) p4[i] = z;
}

// One pass over adj: row partials -> deg_s (atomic), col partials -> deg_t (atomic)
__global__ __launch_bounds__(256)
void adj_deg_kernel(const float* __restrict__ adj,
                    float* __restrict__ deg_s, float* __restrict__ deg_t) {
    const int tid = threadIdx.x;
    const int lane = tid & 63;
    const int c4 = blockIdx.x * 256 + tid;          // float4 column
    const int r0 = blockIdx.y * 32;
    const float4* A4 = (const float4*)adj + (size_t)r0 * (NT / 4) + c4;
    float sx = 0.f, sy = 0.f, sz = 0.f, sw = 0.f;
#pragma unroll 8
    for (int r = 0; r < 32; ++r) {
        float4 v = A4[(size_t)r * (NT / 4)];
        sx += v.x; sy += v.y; sz += v.z; sw += v.w;
        float rp = v.x + v.y + v.z + v.w;
#pragma unroll
        for (int off = 32; off > 0; off >>= 1) rp += __shfl_down(rp, off, 64);
        if (lane == 0) unsafeAtomicAdd(deg_s + r0 + r, rp);
    }
    float* d = deg_t + c4 * 4;
    unsafeAtomicAdd(d + 0, sx);
    unsafeAtomicAdd(d + 1, sy);
    unsafeAtomicAdd(d + 2, sz);
    unsafeAtomicAdd(d + 3, sw);
}

// adj_s row sums -> deg_s (atomic); one wave per row
__global__ __launch_bounds__(256)
void rowsum_s_kernel(const float* __restrict__ adj_s, float* __restrict__ deg_s) {
    const int wid = threadIdx.x >> 6;
    const int lane = threadIdx.x & 63;
    const int row = blockIdx.x * 4 + wid;
    const float4* b = (const float4*)(adj_s + (size_t)row * NS);
    float sum = 0.f;
#pragma unroll 8
    for (int c = lane; c < NS / 4; c += 64) { float4 v = b[c]; sum += v.x + v.y + v.z + v.w; }
#pragma unroll
    for (int off = 32; off > 0; off >>= 1) sum += __shfl_down(sum, off, 64);
    if (lane == 0) unsafeAtomicAdd(deg_s + row, sum);
}

// adj_t col partial sums -> deg_t (atomic); float4 per thread
__global__ __launch_bounds__(256)
void colsum_t_kernel(const float* __restrict__ A, float* __restrict__ deg_t) {
    const int c4 = blockIdx.x * 256 + threadIdx.x;
    const int r0 = blockIdx.y * 64;
    const float4* A4 = (const float4*)A + (size_t)r0 * (NT / 4) + c4;
    float sx = 0.f, sy = 0.f, sz = 0.f, sw = 0.f;
#pragma unroll 8
    for (int r = 0; r < 64; ++r) {
        float4 v = A4[(size_t)r * (NT / 4)];
        sx += v.x; sy += v.y; sz += v.z; sw += v.w;
    }
    float* d = deg_t + c4 * 4;
    unsafeAtomicAdd(d + 0, sx);
    unsafeAtomicAdd(d + 1, sy);
    unsafeAtomicAdd(d + 2, sz);
    unsafeAtomicAdd(d + 3, sw);
}

// deg -> sqrt(deg + 1), in place over rs|rt (contiguous NS+NT)
__global__ void finish_deg_kernel(float* __restrict__ deg) {
    int t = blockIdx.x * blockDim.x + threadIdx.x;
    deg[t] = sqrtf(deg[t] + 1.0f);
}

// out[m,:] = (inp[m,:] @ W) / rdeg[m]  (fp32), plus outT[n][m] = bf16(out[m][n])
__global__ __launch_bounds__(256)
void proj_scale_kernel(const float* __restrict__ inp,
                       const float* __restrict__ W,
                       const float* __restrict__ rdeg,
                       float* __restrict__ outp,
                       ushort* __restrict__ outT, int M) {
    __shared__ float As[32][68];
    __shared__ float Bs[32][128];
    const int tid = threadIdx.x;
    const int m0 = blockIdx.x * 64;
    const int tx = tid & 15, ty = tid >> 4;
    const int arow = tid >> 3, acg = tid & 7;
    const int bk = tid >> 5, bng = tid & 31;

    float acc[4][8];
#pragma unroll
    for (int r = 0; r < 4; ++r)
#pragma unroll
        for (int c = 0; c < 8; ++c) acc[r][c] = 0.f;

    for (int kt = 0; kt < DIN; kt += 32) {
        const float* Ab = inp + (size_t)(m0 + arow) * DIN + kt + acg * 4;
        float4 a0 = *(const float4*)Ab;
        float4 a1 = *(const float4*)(Ab + (size_t)32 * DIN);
        const float* Bb = W + (size_t)(kt + bk) * DOUT + bng * 4;
        float4 b0 = *(const float4*)Bb;
        float4 b1 = *(const float4*)(Bb + 8 * DOUT);
        float4 b2 = *(const float4*)(Bb + 16 * DOUT);
        float4 b3 = *(const float4*)(Bb + 24 * DOUT);
        __syncthreads();
        As[acg * 4 + 0][arow] = a0.x;
        As[acg * 4 + 1][arow] = a0.y;
        As[acg * 4 + 2][arow] = a0.z;
        As[acg * 4 + 3][arow] = a0.w;
        As[acg * 4 + 0][arow + 32] = a1.x;
        As[acg * 4 + 1][arow + 32] = a1.y;
        As[acg * 4 + 2][arow + 32] = a1.z;
        As[acg * 4 + 3][arow + 32] = a1.w;
        *(float4*)&Bs[bk][bng * 4] = b0;
        *(float4*)&Bs[bk + 8][bng * 4] = b1;
        *(float4*)&Bs[bk + 16][bng * 4] = b2;
        *(float4*)&Bs[bk + 24][bng * 4] = b3;
        __syncthreads();
#pragma unroll
        for (int k = 0; k < 32; ++k) {
            float4 av = *(const float4*)&As[k][ty * 4];
            float4 bv0 = *(const float4*)&Bs[k][tx * 4];
            float4 bv1 = *(const float4*)&Bs[k][tx * 4 + 64];
            float a[4] = {av.x, av.y, av.z, av.w};
            float b[8] = {bv0.x, bv0.y, bv0.z, bv0.w, bv1.x, bv1.y, bv1.z, bv1.w};
#pragma unroll
            for (int r = 0; r < 4; ++r)
#pragma unroll
                for (int c = 0; c < 8; ++c) acc[r][c] = fmaf(a[r], b[c], acc[r][c]);
        }
    }
    float rds[4];
#pragma unroll
    for (int r = 0; r < 4; ++r) rds[r] = rdeg[m0 + ty * 4 + r];
#pragma unroll
    for (int r = 0; r < 4; ++r) {
        int row = m0 + ty * 4 + r;
        float* orow = outp + (size_t)row * DOUT;
#pragma unroll
        for (int c = 0; c < 8; ++c) acc[r][c] /= rds[r];
#pragma unroll
        for (int c = 0; c < 4; ++c) {
            orow[tx * 4 + c] = acc[r][c];
            orow[tx * 4 + 64 + c] = acc[r][4 + c];
        }
    }
#pragma unroll
    for (int c = 0; c < 8; ++c) {
        int col = tx * 4 + (c & 3) + (c >> 2) * 64;
        u16x4 w;
#pragma unroll
        for (int r = 0; r < 4; ++r) w[r] = f2bf(acc[r][c]);
        *(u16x4*)&outT[(size_t)col * M + m0 + ty * 4] = w;
    }
}

// C[m0:m0+128, 0:128] += op(A)[m0:m0+128, k0:k0+kchunk] @ B[k0:k0+kchunk, 0:128]
// TRANS=0: op(A)=A row-major pitch lda.  TRANS=1: op(A)=A^T, A[k][m] pitch lda.
// BTF=1: B bf16 transposed bT[n][k] pitch ldb. BTF=0: B fp32 row-major [k][128].
// 2-deep register prefetch: tile k issued ~2 iterations before its LDS store.
template<int TRANS, int BTF>
__global__ __launch_bounds__(256)
void gemm_mfma_kernel(const float* __restrict__ A, int lda,
                      const float* __restrict__ Bf,
                      const ushort* __restrict__ bT, int ldb,
                      float* __restrict__ C, int kchunk) {
    __shared__ ushort As[128][40];   // [m][k], pitch 80 B
    __shared__ ushort Bs[128][40];   // [n][k]
    const int tid = threadIdx.x;
    const int m0 = blockIdx.x * 128;
    const int k0 = blockIdx.y * kchunk;
    const int lane = tid & 63, wid = tid >> 6;
    const int wm = (wid >> 1) * 64, wn = (wid & 1) * 64;
    const int r16 = lane & 15, kg = lane >> 4;

    const int s_kr = tid >> 3, s_f4 = tid & 7;   // fp32-B / TRANS-A staging map
    const int a_r = tid >> 1, a_seg = tid & 1;   // NN-A staging map
    const int t_n = tid >> 2, t_seg = tid & 3;   // bf16-T B staging map

    f32x4 acc[4][4];
#pragma unroll
    for (int i = 0; i < 4; ++i)
#pragma unroll
        for (int j = 0; j < 4; ++j) acc[i][j] = (f32x4)(0.f);

    // two named staging buffers (static indexing only — no runtime-indexed arrays)
    float4 aP0[4], aP1[4], bP0[4], bP1[4];
    bf8v bT0[2], bT1[2];

#define LOADB(bPx, bTx, ktb) do {                                              \
    if (BTF) {                                                                 \
        const ushort* Tb = bT + (size_t)t_n * ldb + k0 + (ktb) + t_seg * 8;    \
        bTx[0] = *(const bf8v*)Tb;                                             \
        bTx[1] = *(const bf8v*)(Tb + (size_t)64 * ldb);                        \
    } else {                                                                   \
        const float* Bb = Bf + (size_t)(k0 + (ktb) + s_kr) * DOUT + s_f4 * 4;  \
        bPx[0] = *(const float4*)(Bb + 0);                                     \
        bPx[1] = *(const float4*)(Bb + 32);                                    \
        bPx[2] = *(const float4*)(Bb + 64);                                    \
        bPx[3] = *(const float4*)(Bb + 96);                                    \
    } } while (0)

#define LOADA(aPx, ktb) do {                                                   \
    if (TRANS) {                                                               \
        const float* Ab = A + (size_t)(k0 + (ktb) + s_kr) * lda + m0 + s_f4 * 4; \
        aPx[0] = *(const float4*)(Ab + 0);                                     \
        aPx[1] = *(const float4*)(Ab + 32);                                    \
        aPx[2] = *(const float4*)(Ab + 64);                                    \
        aPx[3] = *(const float4*)(Ab + 96);                                    \
    } else {                                                                   \
        const float* Ab = A + (size_t)(m0 + a_r) * lda + k0 + (ktb) + a_seg * 16; \
        aPx[0] = *(const float4*)(Ab + 0);                                     \
        aPx[1] = *(const float4*)(Ab + 4);                                     \
        aPx[2] = *(const float4*)(Ab + 8);                                     \
        aPx[3] = *(const float4*)(Ab + 12);                                    \
    } } while (0)

#define STORES(aPx, bPx, bTx) do {                                             \
    if (TRANS) {                                                               \
        _Pragma("unroll")                                                      \
        for (int i = 0; i < 4; ++i) {                                          \
            int m = s_f4 * 4 + i * 32;                                         \
            As[m + 0][s_kr] = f2bf(aPx[i].x);                                  \
            As[m + 1][s_kr] = f2bf(aPx[i].y);                                  \
            As[m + 2][s_kr] = f2bf(aPx[i].z);                                  \
            As[m + 3][s_kr] = f2bf(aPx[i].w);                                  \
        }                                                                      \
    } else {                                                                   \
        bf8v w0, w1;                                                           \
        w0[0] = (short)f2bf(aPx[0].x); w0[1] = (short)f2bf(aPx[0].y);          \
        w0[2] = (short)f2bf(aPx[0].z); w0[3] = (short)f2bf(aPx[0].w);          \
        w0[4] = (short)f2bf(aPx[1].x); w0[5] = (short)f2bf(aPx[1].y);          \
        w0[6] = (short)f2bf(aPx[1].z); w0[7] = (short)f2bf(aPx[1].w);          \
        w1[0] = (short)f2bf(aPx[2].x); w1[1] = (short)f2bf(aPx[2].y);          \
        w1[2] = (short)f2bf(aPx[2].z); w1[3] = (short)f2bf(aPx[2].w);          \
        w1[4] = (short)f2bf(aPx[3].x); w1[5] = (short)f2bf(aPx[3].y);          \
        w1[6] = (short)f2bf(aPx[3].z); w1[7] = (short)f2bf(aPx[3].w);          \
        *(bf8v*)&As[a_r][a_seg * 16] = w0;                                     \
        *(bf8v*)&As[a_r][a_seg * 16 + 8] = w1;                                 \
    }                                                                          \
    if (BTF) {                                                                 \
        *(bf8v*)&Bs[t_n][t_seg * 8] = bTx[0];                                  \
        *(bf8v*)&Bs[t_n + 64][t_seg * 8] = bTx[1];                             \
    } else {                                                                   \
        _Pragma("unroll")                                                      \
        for (int i = 0; i < 4; ++i) {                                          \
            int n = s_f4 * 4 + i * 32;                                         \
            Bs[n + 0][s_kr] = f2bf(bPx[i].x);                                  \
            Bs[n + 1][s_kr] = f2bf(bPx[i].y);                                  \
            Bs[n + 2][s_kr] = f2bf(bPx[i].z);                                  \
            Bs[n + 3][s_kr] = f2bf(bPx[i].w);                                  \
        }                                                                      \
    } } while (0)

#define MFMA_PHASE do {                                                        \
    bf8v af[4], bfv[4];                                                        \
    _Pragma("unroll")                                                          \
    for (int f = 0; f < 4; ++f) af[f] = *(const bf8v*)&As[wm + f * 16 + r16][kg * 8]; \
    _Pragma("unroll")                                                          \
    for (int f = 0; f < 4; ++f) bfv[f] = *(const bf8v*)&Bs[wn + f * 16 + r16][kg * 8]; \
    _Pragma("unroll")                                                          \
    for (int i = 0; i < 4; ++i)                                                \
        _Pragma("unroll")                                                      \
        for (int j = 0; j < 4; ++j)                                            \
            acc[i][j] = __builtin_amdgcn_mfma_f32_16x16x32_bf16(af[i], bfv[j], acc[i][j], 0, 0, 0); \
    } while (0)

    // prologue: 2 tiles in flight
    LOADB(bP0, bT0, 0);  LOADA(aP0, 0);
    LOADB(bP1, bT1, 32); LOADA(aP1, 32);

    for (int kt = 0; kt < kchunk; kt += 64) {
        __syncthreads();
        STORES(aP0, bP0, bT0);
        __syncthreads();
        if (kt + 64 < kchunk) { LOADB(bP0, bT0, kt + 64); LOADA(aP0, kt + 64); }
        MFMA_PHASE;

        __syncthreads();
        STORES(aP1, bP1, bT1);
        __syncthreads();
        if (kt + 96 < kchunk) { LOADB(bP1, bT1, kt + 96); LOADA(aP1, kt + 96); }
        MFMA_PHASE;
    }
#undef LOADB
#undef LOADA
#undef STORES
#undef MFMA_PHASE

    const int crow0 = m0 + wm + (lane >> 4) * 4;
#pragma unroll
    for (int i = 0; i < 4; ++i) {
#pragma unroll
        for (int j = 0; j < 4; ++j) {
            float* base = C + (size_t)(crow0 + i * 16) * DOUT + wn + j * 16 + r16;
            unsafeAtomicAdd(base + 0 * DOUT, acc[i][j][0]);
            unsafeAtomicAdd(base + 1 * DOUT, acc[i][j][1]);
            unsafeAtomicAdd(base + 2 * DOUT, acc[i][j][2]);
            unsafeAtomicAdd(base + 3 * DOUT, acc[i][j][3]);
        }
    }
}

// x_new = relu(xs + C1/rs) -> d_out;  xns = x_new/rs -> ws (fp32)
__global__ void epilogue1_kernel(const float* __restrict__ C1,
                                 const float* __restrict__ xs,
                                 const float* __restrict__ rs,
                                 float* __restrict__ outx,
                                 float* __restrict__ xns) {
    int idx = blockIdx.x * blockDim.x + threadIdx.x;
    if (idx >= NS * DOUT) return;
    int row = idx >> 7;
    float r = rs[row];
    float v = xs[idx] + C1[idx] / r;
    v = v > 0.f ? v : 0.f;
    outx[idx] = v;
    xns[idx] = v / r;
}

// y_new = relu(ys + C2/rt) -> d_out + NS*DOUT
__global__ void epilogue2_kernel(const float* __restrict__ C2,
                                 const float* __restrict__ ys,
                                 const float* __restrict__ rt,
                                 float* __restrict__ outy) {
    int idx = blockIdx.x * blockDim.x + threadIdx.x;
    if (idx >= NT * DOUT) return;
    int row = idx >> 7;
    float v = ys[idx] + C2[idx] / rt[row];
    v = v > 0.f ? v : 0.f;
    outy[idx] = v;
}

extern "C" void kernel_launch(void* const* d_in, const int* in_sizes, int n_in,
                              void* d_out, int out_size, void* d_ws, size_t ws_size,
                              hipStream_t stream) {
    const float* inp_s = (const float*)d_in[0];
    const float* inp_t = (const float*)d_in[1];
    const float* adj   = (const float*)d_in[2];
    const float* adj_s = (const float*)d_in[3];
    const float* adj_t = (const float*)d_in[4];
    const float* W     = (const float*)d_in[5];
    float* out = (float*)d_out;
    float* ws  = (float*)d_ws;

    float* rs  = ws + OFF_RS;
    float* rt  = ws + OFF_RT;
    float* C1  = ws + OFF_C1;
    float* C2  = ws + OFF_C2;
    float* xs  = ws + OFF_XS;
    float* ys  = ws + OFF_YS;
    float* xns = ws + OFF_XNS;
    ushort* xsT = (ushort*)(ws + OFF_XST);
    ushort* ysT = (ushort*)(ws + OFF_YST);

    // zero deg_s + deg_t + C1 + C2 (contiguous [0, OFF_XS))
    zero_kernel<<<1024, 256, 0, stream>>>(ws, OFF_XS / 4);

    // Degree pass, ordered for LLC residency in the GEMM phase:
    // stream adj_t (268 MB) FIRST so adj (134 MB) + adj_s (67 MB) stay resident.
    colsum_t_kernel<<<dim3(NT / 1024, NT / 64), 256, 0, stream>>>(adj_t, rt);
    adj_deg_kernel<<<dim3(NT / 1024, NS / 32), 256, 0, stream>>>(adj, rs, rt);
    rowsum_s_kernel<<<NS / 4, 256, 0, stream>>>(adj_s, rs);
    finish_deg_kernel<<<(NS + NT) / 256, 256, 0, stream>>>(rs);   // rs|rt contiguous

    // projections: xs = (inp_s@W)/rs (fp32) + xsT (bf16 transposed); same for ys
    proj_scale_kernel<<<NS / 64, 256, 0, stream>>>(inp_s, W, rs, xs, xsT, NS);
    proj_scale_kernel<<<NT / 64, 256, 0, stream>>>(inp_t, W, rt, ys, ysT, NT);

    // GEMMs ordered LLC-warm first, adj_t (cold, 268 MB) last.
    // C1 = adj_s@xs + adj@ys   [NS,128]
    gemm_mfma_kernel<0, 1><<<dim3(NS / 128, 8), 256, 0, stream>>>(adj_s, NS, nullptr, xsT, NS, C1, NS / 8);
    gemm_mfma_kernel<0, 1><<<dim3(NS / 128, 8), 256, 0, stream>>>(adj, NT, nullptr, ysT, NT, C1, NT / 8);
    epilogue1_kernel<<<(NS * DOUT) / 256, 256, 0, stream>>>(C1, xs, rs, out, xns);

    // C2 = adj^T@xns + adj_t@ys   [NT,128]
    gemm_mfma_kernel<1, 0><<<dim3(NT / 128, 8), 256, 0, stream>>>(adj, NT, xns, nullptr, 0, C2, NS / 8);
    gemm_mfma_kernel<0, 1><<<dim3(NT / 128, 8), 256, 0, stream>>>(adj_t, NT, nullptr, ysT, NT, C2, NT / 8);
    epilogue2_kernel<<<(NT * DOUT) / 256, 256, 0, stream>>>(C2, ys, rt, out + NS * DOUT);
}

// Round 12
// 360.908 us; speedup vs baseline: 1.1064x; 1.0647x over previous
//
#include <hip/hip_runtime.h>

#define NS 4096
#define NT 8192
#define DIN 256
#define DOUT 128

// float offsets into workspace
#define OFF_RS   0                       // deg_s then rs in place [NS]
#define OFF_RT   (NS)                    // deg_t then rt in place [NT]
#define OFF_C1   (OFF_RT + NT)
#define OFF_C2   (OFF_C1 + NS*DOUT)
#define OFF_XS   (OFF_C2 + NT*DOUT)
#define OFF_YS   (OFF_XS + NS*DOUT)
#define OFF_XNS  (OFF_YS + NT*DOUT)
#define OFF_XST  (OFF_XNS + NS*DOUT)               // bf16 [128][NS]
#define OFF_YST  (OFF_XST + (128*NS)/2)            // bf16 [128][NT]

typedef __attribute__((ext_vector_type(8))) short bf8v;
typedef __attribute__((ext_vector_type(4))) float f32x4;
typedef __attribute__((ext_vector_type(4))) unsigned short u16x4;

__device__ __forceinline__ ushort f2bf(float f) {
    // exact round-to-nearest-even fp32 -> bf16 (finite inputs only)
    unsigned x = __float_as_uint(f);
    unsigned r = (x + 0x7fffu + ((x >> 16) & 1u)) >> 16;
    return (ushort)r;
}

__global__ void zero_kernel(float* __restrict__ p, int n4) {
    int i = blockIdx.x * blockDim.x + threadIdx.x;
    int stride = gridDim.x * blockDim.x;
    float4* p4 = (float4*)p;
    float4 z = make_float4(0.f, 0.f, 0.f, 0.f);
    for (; i < n4; i += stride) p4[i] = z;
}

// One pass over adj: row partials -> deg_s (atomic), col partials -> deg_t (atomic)
__global__ __launch_bounds__(256)
void adj_deg_kernel(const float* __restrict__ adj,
                    float* __restrict__ deg_s, float* __restrict__ deg_t) {
    const int tid = threadIdx.x;
    const int lane = tid & 63;
    const int c4 = blockIdx.x * 256 + tid;          // float4 column
    const int r0 = blockIdx.y * 32;
    const float4* A4 = (const float4*)adj + (size_t)r0 * (NT / 4) + c4;
    float sx = 0.f, sy = 0.f, sz = 0.f, sw = 0.f;
#pragma unroll 8
    for (int r = 0; r < 32; ++r) {
        float4 v = A4[(size_t)r * (NT / 4)];
        sx += v.x; sy += v.y; sz += v.z; sw += v.w;
        float rp = v.x + v.y + v.z + v.w;
#pragma unroll
        for (int off = 32; off > 0; off >>= 1) rp += __shfl_down(rp, off, 64);
        if (lane == 0) unsafeAtomicAdd(deg_s + r0 + r, rp);
    }
    float* d = deg_t + c4 * 4;
    unsafeAtomicAdd(d + 0, sx);
    unsafeAtomicAdd(d + 1, sy);
    unsafeAtomicAdd(d + 2, sz);
    unsafeAtomicAdd(d + 3, sw);
}

// adj_s row sums -> deg_s (atomic); one wave per row
__global__ __launch_bounds__(256)
void rowsum_s_kernel(const float* __restrict__ adj_s, float* __restrict__ deg_s) {
    const int wid = threadIdx.x >> 6;
    const int lane = threadIdx.x & 63;
    const int row = blockIdx.x * 4 + wid;
    const float4* b = (const float4*)(adj_s + (size_t)row * NS);
    float sum = 0.f;
#pragma unroll 8
    for (int c = lane; c < NS / 4; c += 64) { float4 v = b[c]; sum += v.x + v.y + v.z + v.w; }
#pragma unroll
    for (int off = 32; off > 0; off >>= 1) sum += __shfl_down(sum, off, 64);
    if (lane == 0) unsafeAtomicAdd(deg_s + row, sum);
}

// adj_t col partial sums -> deg_t (atomic); float4 per thread
__global__ __launch_bounds__(256)
void colsum_t_kernel(const float* __restrict__ A, float* __restrict__ deg_t) {
    const int c4 = blockIdx.x * 256 + threadIdx.x;
    const int r0 = blockIdx.y * 64;
    const float4* A4 = (const float4*)A + (size_t)r0 * (NT / 4) + c4;
    float sx = 0.f, sy = 0.f, sz = 0.f, sw = 0.f;
#pragma unroll 8
    for (int r = 0; r < 64; ++r) {
        float4 v = A4[(size_t)r * (NT / 4)];
        sx += v.x; sy += v.y; sz += v.z; sw += v.w;
    }
    float* d = deg_t + c4 * 4;
    unsafeAtomicAdd(d + 0, sx);
    unsafeAtomicAdd(d + 1, sy);
    unsafeAtomicAdd(d + 2, sz);
    unsafeAtomicAdd(d + 3, sw);
}

// deg -> sqrt(deg + 1), in place over rs|rt (contiguous NS+NT)
__global__ void finish_deg_kernel(float* __restrict__ deg) {
    int t = blockIdx.x * blockDim.x + threadIdx.x;
    deg[t] = sqrtf(deg[t] + 1.0f);
}

// out[m,:] = (inp[m,:] @ W) / rdeg[m]  (fp32), plus outT[n][m] = bf16(out[m][n])
__global__ __launch_bounds__(256)
void proj_scale_kernel(const float* __restrict__ inp,
                       const float* __restrict__ W,
                       const float* __restrict__ rdeg,
                       float* __restrict__ outp,
                       ushort* __restrict__ outT, int M) {
    __shared__ float As[32][68];
    __shared__ float Bs[32][128];
    const int tid = threadIdx.x;
    const int m0 = blockIdx.x * 64;
    const int tx = tid & 15, ty = tid >> 4;
    const int arow = tid >> 3, acg = tid & 7;
    const int bk = tid >> 5, bng = tid & 31;

    float acc[4][8];
#pragma unroll
    for (int r = 0; r < 4; ++r)
#pragma unroll
        for (int c = 0; c < 8; ++c) acc[r][c] = 0.f;

    for (int kt = 0; kt < DIN; kt += 32) {
        const float* Ab = inp + (size_t)(m0 + arow) * DIN + kt + acg * 4;
        float4 a0 = *(const float4*)Ab;
        float4 a1 = *(const float4*)(Ab + (size_t)32 * DIN);
        const float* Bb = W + (size_t)(kt + bk) * DOUT + bng * 4;
        float4 b0 = *(const float4*)Bb;
        float4 b1 = *(const float4*)(Bb + 8 * DOUT);
        float4 b2 = *(const float4*)(Bb + 16 * DOUT);
        float4 b3 = *(const float4*)(Bb + 24 * DOUT);
        __syncthreads();
        As[acg * 4 + 0][arow] = a0.x;
        As[acg * 4 + 1][arow] = a0.y;
        As[acg * 4 + 2][arow] = a0.z;
        As[acg * 4 + 3][arow] = a0.w;
        As[acg * 4 + 0][arow + 32] = a1.x;
        As[acg * 4 + 1][arow + 32] = a1.y;
        As[acg * 4 + 2][arow + 32] = a1.z;
        As[acg * 4 + 3][arow + 32] = a1.w;
        *(float4*)&Bs[bk][bng * 4] = b0;
        *(float4*)&Bs[bk + 8][bng * 4] = b1;
        *(float4*)&Bs[bk + 16][bng * 4] = b2;
        *(float4*)&Bs[bk + 24][bng * 4] = b3;
        __syncthreads();
#pragma unroll
        for (int k = 0; k < 32; ++k) {
            float4 av = *(const float4*)&As[k][ty * 4];
            float4 bv0 = *(const float4*)&Bs[k][tx * 4];
            float4 bv1 = *(const float4*)&Bs[k][tx * 4 + 64];
            float a[4] = {av.x, av.y, av.z, av.w};
            float b[8] = {bv0.x, bv0.y, bv0.z, bv0.w, bv1.x, bv1.y, bv1.z, bv1.w};
#pragma unroll
            for (int r = 0; r < 4; ++r)
#pragma unroll
                for (int c = 0; c < 8; ++c) acc[r][c] = fmaf(a[r], b[c], acc[r][c]);
        }
    }
    float rds[4];
#pragma unroll
    for (int r = 0; r < 4; ++r) rds[r] = rdeg[m0 + ty * 4 + r];
#pragma unroll
    for (int r = 0; r < 4; ++r) {
        int row = m0 + ty * 4 + r;
        float* orow = outp + (size_t)row * DOUT;
#pragma unroll
        for (int c = 0; c < 8; ++c) acc[r][c] /= rds[r];
#pragma unroll
        for (int c = 0; c < 4; ++c) {
            orow[tx * 4 + c] = acc[r][c];
            orow[tx * 4 + 64 + c] = acc[r][4 + c];
        }
    }
#pragma unroll
    for (int c = 0; c < 8; ++c) {
        int col = tx * 4 + (c & 3) + (c >> 2) * 64;
        u16x4 w;
#pragma unroll
        for (int r = 0; r < 4; ++r) w[r] = f2bf(acc[r][c]);
        *(u16x4*)&outT[(size_t)col * M + m0 + ty * 4] = w;
    }
}

// One 128x128 output tile over one K-chunk; the r8-proven GEMM body.
// TRANS=0: A[m][k] pitch lda.  TRANS=1: op(A)=A^T with A[k][m] pitch lda.
// BTF=1: B bf16 transposed bT[n][k] pitch ldb.  BTF=0: B fp32 row-major [k][128].
template<int TRANS, int BTF>
__device__ __forceinline__
void gemm_body(ushort (*As)[40], ushort (*Bs)[40],
               const float* __restrict__ A, int lda,
               const float* __restrict__ Bf,
               const ushort* __restrict__ bT, int ldb,
               float* __restrict__ C, int kchunk, int k0, int m0) {
    const int tid = threadIdx.x;
    const int lane = tid & 63, wid = tid >> 6;
    const int wm = (wid >> 1) * 64, wn = (wid & 1) * 64;
    const int r16 = lane & 15, kg = lane >> 4;

    const int s_kr = tid >> 3, s_f4 = tid & 7;   // fp32-B / TRANS-A staging map
    const int a_r = tid >> 1, a_seg = tid & 1;   // NN-A staging map
    const int t_n = tid >> 2, t_seg = tid & 3;   // bf16-T B staging map

    f32x4 acc[4][4];
#pragma unroll
    for (int i = 0; i < 4; ++i)
#pragma unroll
        for (int j = 0; j < 4; ++j) acc[i][j] = (f32x4)(0.f);

    float4 aP[4], bP[4];
    bf8v bPT[2];

    auto loadB = [&](int ktb) {
        if (BTF) {
            const ushort* Tb = bT + (size_t)t_n * ldb + k0 + ktb + t_seg * 8;
            bPT[0] = *(const bf8v*)Tb;
            bPT[1] = *(const bf8v*)(Tb + (size_t)64 * ldb);
        } else {
            const float* Bb = Bf + (size_t)(k0 + ktb + s_kr) * DOUT + s_f4 * 4;
#pragma unroll
            for (int i = 0; i < 4; ++i) bP[i] = *(const float4*)(Bb + i * 32);
        }
    };
    auto loadA = [&](int ktb) {
        if (TRANS) {
            const float* Ab = A + (size_t)(k0 + ktb + s_kr) * lda + m0 + s_f4 * 4;
#pragma unroll
            for (int i = 0; i < 4; ++i) aP[i] = *(const float4*)(Ab + i * 32);
        } else {
            const float* Ab = A + (size_t)(m0 + a_r) * lda + k0 + ktb + a_seg * 16;
#pragma unroll
            for (int i = 0; i < 4; ++i) aP[i] = *(const float4*)(Ab + i * 4);
        }
    };

    loadB(0); loadA(0);

    for (int kt = 0; kt < kchunk; kt += 32) {
        __syncthreads();
        if (TRANS) {
#pragma unroll
            for (int i = 0; i < 4; ++i) {
                int m = s_f4 * 4 + i * 32;
                As[m + 0][s_kr] = f2bf(aP[i].x);
                As[m + 1][s_kr] = f2bf(aP[i].y);
                As[m + 2][s_kr] = f2bf(aP[i].z);
                As[m + 3][s_kr] = f2bf(aP[i].w);
            }
        } else {
            bf8v w0, w1;
            w0[0] = (short)f2bf(aP[0].x); w0[1] = (short)f2bf(aP[0].y);
            w0[2] = (short)f2bf(aP[0].z); w0[3] = (short)f2bf(aP[0].w);
            w0[4] = (short)f2bf(aP[1].x); w0[5] = (short)f2bf(aP[1].y);
            w0[6] = (short)f2bf(aP[1].z); w0[7] = (short)f2bf(aP[1].w);
            w1[0] = (short)f2bf(aP[2].x); w1[1] = (short)f2bf(aP[2].y);
            w1[2] = (short)f2bf(aP[2].z); w1[3] = (short)f2bf(aP[2].w);
            w1[4] = (short)f2bf(aP[3].x); w1[5] = (short)f2bf(aP[3].y);
            w1[6] = (short)f2bf(aP[3].z); w1[7] = (short)f2bf(aP[3].w);
            *(bf8v*)&As[a_r][a_seg * 16] = w0;
            *(bf8v*)&As[a_r][a_seg * 16 + 8] = w1;
        }
        if (BTF) {
            *(bf8v*)&Bs[t_n][t_seg * 8] = bPT[0];
            *(bf8v*)&Bs[t_n + 64][t_seg * 8] = bPT[1];
        } else {
#pragma unroll
            for (int i = 0; i < 4; ++i) {
                int n = s_f4 * 4 + i * 32;
                Bs[n + 0][s_kr] = f2bf(bP[i].x);
                Bs[n + 1][s_kr] = f2bf(bP[i].y);
                Bs[n + 2][s_kr] = f2bf(bP[i].z);
                Bs[n + 3][s_kr] = f2bf(bP[i].w);
            }
        }
        __syncthreads();

        if (kt + 32 < kchunk) { loadB(kt + 32); loadA(kt + 32); }

        bf8v af[4], bfv[4];
#pragma unroll
        for (int f = 0; f < 4; ++f) af[f] = *(const bf8v*)&As[wm + f * 16 + r16][kg * 8];
#pragma unroll
        for (int f = 0; f < 4; ++f) bfv[f] = *(const bf8v*)&Bs[wn + f * 16 + r16][kg * 8];
#pragma unroll
        for (int i = 0; i < 4; ++i)
#pragma unroll
            for (int j = 0; j < 4; ++j)
                acc[i][j] = __builtin_amdgcn_mfma_f32_16x16x32_bf16(af[i], bfv[j], acc[i][j], 0, 0, 0);
    }

    const int crow0 = m0 + wm + (lane >> 4) * 4;
#pragma unroll
    for (int i = 0; i < 4; ++i) {
#pragma unroll
        for (int j = 0; j < 4; ++j) {
            float* base = C + (size_t)(crow0 + i * 16) * DOUT + wn + j * 16 + r16;
            unsafeAtomicAdd(base + 0 * DOUT, acc[i][j][0]);
            unsafeAtomicAdd(base + 1 * DOUT, acc[i][j][1]);
            unsafeAtomicAdd(base + 2 * DOUT, acc[i][j][2]);
            unsafeAtomicAdd(base + 3 * DOUT, acc[i][j][3]);
        }
    }
}

// Two independent GEMMs accumulating into the same C, co-scheduled in one grid:
// blockIdx.y < nsplit0 -> part 0 (split blockIdx.y), else part 1 (split y-nsplit0).
template<int TRANS0, int BTF0, int TRANS1, int BTF1>
__global__ __launch_bounds__(256)
void gemm_dual_kernel(const float* __restrict__ A0, int lda0,
                      const float* __restrict__ B0f, const ushort* __restrict__ B0T, int ldb0,
                      int kchunk0, int nsplit0,
                      const float* __restrict__ A1, int lda1,
                      const float* __restrict__ B1f, const ushort* __restrict__ B1T, int ldb1,
                      int kchunk1,
                      float* __restrict__ C) {
    __shared__ ushort As[128][40];
    __shared__ ushort Bs[128][40];
    const int m0 = blockIdx.x * 128;
    const int y = blockIdx.y;
    if (y < nsplit0) {
        gemm_body<TRANS0, BTF0>(As, Bs, A0, lda0, B0f, B0T, ldb0, C, kchunk0, y * kchunk0, m0);
    } else {
        gemm_body<TRANS1, BTF1>(As, Bs, A1, lda1, B1f, B1T, ldb1, C, kchunk1, (y - nsplit0) * kchunk1, m0);
    }
}

// x_new = relu(xs + C1/rs) -> d_out;  xns = x_new/rs -> ws (fp32)
__global__ void epilogue1_kernel(const float* __restrict__ C1,
                                 const float* __restrict__ xs,
                                 const float* __restrict__ rs,
                                 float* __restrict__ outx,
                                 float* __restrict__ xns) {
    int idx = blockIdx.x * blockDim.x + threadIdx.x;
    if (idx >= NS * DOUT) return;
    int row = idx >> 7;
    float r = rs[row];
    float v = xs[idx] + C1[idx] / r;
    v = v > 0.f ? v : 0.f;
    outx[idx] = v;
    xns[idx] = v / r;
}

// y_new = relu(ys + C2/rt) -> d_out + NS*DOUT
__global__ void epilogue2_kernel(const float* __restrict__ C2,
                                 const float* __restrict__ ys,
                                 const float* __restrict__ rt,
                                 float* __restrict__ outy) {
    int idx = blockIdx.x * blockDim.x + threadIdx.x;
    if (idx >= NT * DOUT) return;
    int row = idx >> 7;
    float v = ys[idx] + C2[idx] / rt[row];
    v = v > 0.f ? v : 0.f;
    outy[idx] = v;
}

extern "C" void kernel_launch(void* const* d_in, const int* in_sizes, int n_in,
                              void* d_out, int out_size, void* d_ws, size_t ws_size,
                              hipStream_t stream) {
    const float* inp_s = (const float*)d_in[0];
    const float* inp_t = (const float*)d_in[1];
    const float* adj   = (const float*)d_in[2];
    const float* adj_s = (const float*)d_in[3];
    const float* adj_t = (const float*)d_in[4];
    const float* W     = (const float*)d_in[5];
    float* out = (float*)d_out;
    float* ws  = (float*)d_ws;

    float* rs  = ws + OFF_RS;
    float* rt  = ws + OFF_RT;
    float* C1  = ws + OFF_C1;
    float* C2  = ws + OFF_C2;
    float* xs  = ws + OFF_XS;
    float* ys  = ws + OFF_YS;
    float* xns = ws + OFF_XNS;
    ushort* xsT = (ushort*)(ws + OFF_XST);
    ushort* ysT = (ushort*)(ws + OFF_YST);

    // zero deg_s + deg_t + C1 + C2 (contiguous [0, OFF_XS))
    zero_kernel<<<1024, 256, 0, stream>>>(ws, OFF_XS / 4);

    // Degree pass, ordered for LLC residency in the GEMM phase:
    // stream adj_t (268 MB) FIRST so adj (134 MB) + adj_s (67 MB) stay resident.
    colsum_t_kernel<<<dim3(NT / 1024, NT / 64), 256, 0, stream>>>(adj_t, rt);
    adj_deg_kernel<<<dim3(NT / 1024, NS / 32), 256, 0, stream>>>(adj, rs, rt);
    rowsum_s_kernel<<<NS / 4, 256, 0, stream>>>(adj_s, rs);
    finish_deg_kernel<<<(NS + NT) / 256, 256, 0, stream>>>(rs);   // rs|rt contiguous

    // projections: xs = (inp_s@W)/rs (fp32) + xsT (bf16 transposed); same for ys
    proj_scale_kernel<<<NS / 64, 256, 0, stream>>>(inp_s, W, rs, xs, xsT, NS);
    proj_scale_kernel<<<NT / 64, 256, 0, stream>>>(inp_t, W, rt, ys, ysT, NT);

    // C1 = adj_s@xs + adj@ys, both sub-GEMMs co-scheduled (512 blocks = 2/CU)
    gemm_dual_kernel<0, 1, 0, 1><<<dim3(NS / 128, 16), 256, 0, stream>>>(
        adj_s, NS, nullptr, xsT, NS, NS / 8, 8,
        adj,   NT, nullptr, ysT, NT, NT / 8, C1);
    epilogue1_kernel<<<(NS * DOUT) / 256, 256, 0, stream>>>(C1, xs, rs, out, xns);

    // C2 = adj^T@xns + adj_t@ys, co-scheduled (1024 blocks = 4/CU)
    gemm_dual_kernel<1, 0, 0, 1><<<dim3(NT / 128, 16), 256, 0, stream>>>(
        adj,   NT, xns, nullptr, 0, NS / 8, 8,
        adj_t, NT, nullptr, ysT, NT, NT / 8, C2);
    epilogue2_kernel<<<(NT * DOUT) / 256, 256, 0, stream>>>(C2, ys, rt, out + NS * DOUT);
}

// Round 13
// 352.886 us; speedup vs baseline: 1.1316x; 1.0227x over previous
//
#include <hip/hip_runtime.h>

#define NS 4096
#define NT 8192
#define DIN 256
#define DOUT 128

// float offsets into workspace
#define OFF_RS   0                       // deg_s then rs in place [NS]
#define OFF_RT   (NS)                    // deg_t then rt in place [NT]
#define OFF_C1   (OFF_RT + NT)
#define OFF_C2   (OFF_C1 + NS*DOUT)
#define OFF_XS   (OFF_C2 + NT*DOUT)
#define OFF_YS   (OFF_XS + NS*DOUT)
#define OFF_XNS  (OFF_YS + NT*DOUT)
#define OFF_XST  (OFF_XNS + NS*DOUT)               // bf16 [128][NS]
#define OFF_YST  (OFF_XST + (128*NS)/2)            // bf16 [128][NT]

typedef __attribute__((ext_vector_type(8))) short bf8v;
typedef __attribute__((ext_vector_type(4))) float f32x4;
typedef __attribute__((ext_vector_type(4))) unsigned short u16x4;

__device__ __forceinline__ ushort f2bf(float f) {
    // exact round-to-nearest-even fp32 -> bf16 (finite inputs only)
    unsigned x = __float_as_uint(f);
    unsigned r = (x + 0x7fffu + ((x >> 16) & 1u)) >> 16;
    return (ushort)r;
}

__global__ void zero_kernel(float* __restrict__ p, int n4) {
    int i = blockIdx.x * blockDim.x + threadIdx.x;
    int stride = gridDim.x * blockDim.x;
    float4* p4 = (float4*)p;
    float4 z = make_float4(0.f, 0.f, 0.f, 0.f);
    for (; i < n4; i += stride) p4[i] = z;
}

// One pass over adj: row partials -> deg_s (atomic), col partials -> deg_t (atomic)
__global__ __launch_bounds__(256)
void adj_deg_kernel(const float* __restrict__ adj,
                    float* __restrict__ deg_s, float* __restrict__ deg_t) {
    const int tid = threadIdx.x;
    const int lane = tid & 63;
    const int c4 = blockIdx.x * 256 + tid;          // float4 column
    const int r0 = blockIdx.y * 32;
    const float4* A4 = (const float4*)adj + (size_t)r0 * (NT / 4) + c4;
    float sx = 0.f, sy = 0.f, sz = 0.f, sw = 0.f;
#pragma unroll 8
    for (int r = 0; r < 32; ++r) {
        float4 v = A4[(size_t)r * (NT / 4)];
        sx += v.x; sy += v.y; sz += v.z; sw += v.w;
        float rp = v.x + v.y + v.z + v.w;
#pragma unroll
        for (int off = 32; off > 0; off >>= 1) rp += __shfl_down(rp, off, 64);
        if (lane == 0) unsafeAtomicAdd(deg_s + r0 + r, rp);
    }
    float* d = deg_t + c4 * 4;
    unsafeAtomicAdd(d + 0, sx);
    unsafeAtomicAdd(d + 1, sy);
    unsafeAtomicAdd(d + 2, sz);
    unsafeAtomicAdd(d + 3, sw);
}

// adj_s row sums -> deg_s (atomic); one wave per row
__global__ __launch_bounds__(256)
void rowsum_s_kernel(const float* __restrict__ adj_s, float* __restrict__ deg_s) {
    const int wid = threadIdx.x >> 6;
    const int lane = threadIdx.x & 63;
    const int row = blockIdx.x * 4 + wid;
    const float4* b = (const float4*)(adj_s + (size_t)row * NS);
    float sum = 0.f;
#pragma unroll 8
    for (int c = lane; c < NS / 4; c += 64) { float4 v = b[c]; sum += v.x + v.y + v.z + v.w; }
#pragma unroll
    for (int off = 32; off > 0; off >>= 1) sum += __shfl_down(sum, off, 64);
    if (lane == 0) unsafeAtomicAdd(deg_s + row, sum);
}

// adj_t col partial sums -> deg_t (atomic); float4 per thread
__global__ __launch_bounds__(256)
void colsum_t_kernel(const float* __restrict__ A, float* __restrict__ deg_t) {
    const int c4 = blockIdx.x * 256 + threadIdx.x;
    const int r0 = blockIdx.y * 64;
    const float4* A4 = (const float4*)A + (size_t)r0 * (NT / 4) + c4;
    float sx = 0.f, sy = 0.f, sz = 0.f, sw = 0.f;
#pragma unroll 8
    for (int r = 0; r < 64; ++r) {
        float4 v = A4[(size_t)r * (NT / 4)];
        sx += v.x; sy += v.y; sz += v.z; sw += v.w;
    }
    float* d = deg_t + c4 * 4;
    unsafeAtomicAdd(d + 0, sx);
    unsafeAtomicAdd(d + 1, sy);
    unsafeAtomicAdd(d + 2, sz);
    unsafeAtomicAdd(d + 3, sw);
}

// deg -> sqrt(deg + 1), in place over rs|rt (contiguous NS+NT)
__global__ void finish_deg_kernel(float* __restrict__ deg) {
    int t = blockIdx.x * blockDim.x + threadIdx.x;
    deg[t] = sqrtf(deg[t] + 1.0f);
}

// out[m,:] = (inp[m,:] @ W) / rdeg[m]  (fp32), plus outT[n][m] = bf16(out[m][n])
__global__ __launch_bounds__(256)
void proj_scale_kernel(const float* __restrict__ inp,
                       const float* __restrict__ W,
                       const float* __restrict__ rdeg,
                       float* __restrict__ outp,
                       ushort* __restrict__ outT, int M) {
    __shared__ float As[32][68];
    __shared__ float Bs[32][128];
    const int tid = threadIdx.x;
    const int m0 = blockIdx.x * 64;
    const int tx = tid & 15, ty = tid >> 4;
    const int arow = tid >> 3, acg = tid & 7;
    const int bk = tid >> 5, bng = tid & 31;

    float acc[4][8];
#pragma unroll
    for (int r = 0; r < 4; ++r)
#pragma unroll
        for (int c = 0; c < 8; ++c) acc[r][c] = 0.f;

    for (int kt = 0; kt < DIN; kt += 32) {
        const float* Ab = inp + (size_t)(m0 + arow) * DIN + kt + acg * 4;
        float4 a0 = *(const float4*)Ab;
        float4 a1 = *(const float4*)(Ab + (size_t)32 * DIN);
        const float* Bb = W + (size_t)(kt + bk) * DOUT + bng * 4;
        float4 b0 = *(const float4*)Bb;
        float4 b1 = *(const float4*)(Bb + 8 * DOUT);
        float4 b2 = *(const float4*)(Bb + 16 * DOUT);
        float4 b3 = *(const float4*)(Bb + 24 * DOUT);
        __syncthreads();
        As[acg * 4 + 0][arow] = a0.x;
        As[acg * 4 + 1][arow] = a0.y;
        As[acg * 4 + 2][arow] = a0.z;
        As[acg * 4 + 3][arow] = a0.w;
        As[acg * 4 + 0][arow + 32] = a1.x;
        As[acg * 4 + 1][arow + 32] = a1.y;
        As[acg * 4 + 2][arow + 32] = a1.z;
        As[acg * 4 + 3][arow + 32] = a1.w;
        *(float4*)&Bs[bk][bng * 4] = b0;
        *(float4*)&Bs[bk + 8][bng * 4] = b1;
        *(float4*)&Bs[bk + 16][bng * 4] = b2;
        *(float4*)&Bs[bk + 24][bng * 4] = b3;
        __syncthreads();
#pragma unroll
        for (int k = 0; k < 32; ++k) {
            float4 av = *(const float4*)&As[k][ty * 4];
            float4 bv0 = *(const float4*)&Bs[k][tx * 4];
            float4 bv1 = *(const float4*)&Bs[k][tx * 4 + 64];
            float a[4] = {av.x, av.y, av.z, av.w};
            float b[8] = {bv0.x, bv0.y, bv0.z, bv0.w, bv1.x, bv1.y, bv1.z, bv1.w};
#pragma unroll
            for (int r = 0; r < 4; ++r)
#pragma unroll
                for (int c = 0; c < 8; ++c) acc[r][c] = fmaf(a[r], b[c], acc[r][c]);
        }
    }
    float rds[4];
#pragma unroll
    for (int r = 0; r < 4; ++r) rds[r] = rdeg[m0 + ty * 4 + r];
#pragma unroll
    for (int r = 0; r < 4; ++r) {
        int row = m0 + ty * 4 + r;
        float* orow = outp + (size_t)row * DOUT;
#pragma unroll
        for (int c = 0; c < 8; ++c) acc[r][c] /= rds[r];
#pragma unroll
        for (int c = 0; c < 4; ++c) {
            orow[tx * 4 + c] = acc[r][c];
            orow[tx * 4 + 64 + c] = acc[r][4 + c];
        }
    }
#pragma unroll
    for (int c = 0; c < 8; ++c) {
        int col = tx * 4 + (c & 3) + (c >> 2) * 64;
        u16x4 w;
#pragma unroll
        for (int r = 0; r < 4; ++r) w[r] = f2bf(acc[r][c]);
        *(u16x4*)&outT[(size_t)col * M + m0 + ty * 4] = w;
    }
}

// One 128x128 output tile over one K-chunk; the r8-proven GEMM body.
// TRANS=0: A[m][k] pitch lda.  TRANS=1: op(A)=A^T with A[k][m] pitch lda.
// BTF=1: B bf16 transposed bT[n][k] pitch ldb.  BTF=0: B fp32 row-major [k][128].
template<int TRANS, int BTF>
__device__ __forceinline__
void gemm_body(ushort (*As)[40], ushort (*Bs)[40],
               const float* __restrict__ A, int lda,
               const float* __restrict__ Bf,
               const ushort* __restrict__ bT, int ldb,
               float* __restrict__ C, int kchunk, int k0, int m0) {
    const int tid = threadIdx.x;
    const int lane = tid & 63, wid = tid >> 6;
    const int wm = (wid >> 1) * 64, wn = (wid & 1) * 64;
    const int r16 = lane & 15, kg = lane >> 4;

    const int s_kr = tid >> 3, s_f4 = tid & 7;   // fp32-B / TRANS-A staging map
    const int a_r = tid >> 1, a_seg = tid & 1;   // NN-A staging map
    const int t_n = tid >> 2, t_seg = tid & 3;   // bf16-T B staging map

    f32x4 acc[4][4];
#pragma unroll
    for (int i = 0; i < 4; ++i)
#pragma unroll
        for (int j = 0; j < 4; ++j) acc[i][j] = (f32x4)(0.f);

    float4 aP[4], bP[4];
    bf8v bPT[2];

    auto loadB = [&](int ktb) {
        if (BTF) {
            const ushort* Tb = bT + (size_t)t_n * ldb + k0 + ktb + t_seg * 8;
            bPT[0] = *(const bf8v*)Tb;
            bPT[1] = *(const bf8v*)(Tb + (size_t)64 * ldb);
        } else {
            const float* Bb = Bf + (size_t)(k0 + ktb + s_kr) * DOUT + s_f4 * 4;
#pragma unroll
            for (int i = 0; i < 4; ++i) bP[i] = *(const float4*)(Bb + i * 32);
        }
    };
    auto loadA = [&](int ktb) {
        if (TRANS) {
            const float* Ab = A + (size_t)(k0 + ktb + s_kr) * lda + m0 + s_f4 * 4;
#pragma unroll
            for (int i = 0; i < 4; ++i) aP[i] = *(const float4*)(Ab + i * 32);
        } else {
            const float* Ab = A + (size_t)(m0 + a_r) * lda + k0 + ktb + a_seg * 16;
#pragma unroll
            for (int i = 0; i < 4; ++i) aP[i] = *(const float4*)(Ab + i * 4);
        }
    };

    loadB(0); loadA(0);

    for (int kt = 0; kt < kchunk; kt += 32) {
        __syncthreads();
        if (TRANS) {
#pragma unroll
            for (int i = 0; i < 4; ++i) {
                int m = s_f4 * 4 + i * 32;
                As[m + 0][s_kr] = f2bf(aP[i].x);
                As[m + 1][s_kr] = f2bf(aP[i].y);
                As[m + 2][s_kr] = f2bf(aP[i].z);
                As[m + 3][s_kr] = f2bf(aP[i].w);
            }
        } else {
            bf8v w0, w1;
            w0[0] = (short)f2bf(aP[0].x); w0[1] = (short)f2bf(aP[0].y);
            w0[2] = (short)f2bf(aP[0].z); w0[3] = (short)f2bf(aP[0].w);
            w0[4] = (short)f2bf(aP[1].x); w0[5] = (short)f2bf(aP[1].y);
            w0[6] = (short)f2bf(aP[1].z); w0[7] = (short)f2bf(aP[1].w);
            w1[0] = (short)f2bf(aP[2].x); w1[1] = (short)f2bf(aP[2].y);
            w1[2] = (short)f2bf(aP[2].z); w1[3] = (short)f2bf(aP[2].w);
            w1[4] = (short)f2bf(aP[3].x); w1[5] = (short)f2bf(aP[3].y);
            w1[6] = (short)f2bf(aP[3].z); w1[7] = (short)f2bf(aP[3].w);
            *(bf8v*)&As[a_r][a_seg * 16] = w0;
            *(bf8v*)&As[a_r][a_seg * 16 + 8] = w1;
        }
        if (BTF) {
            *(bf8v*)&Bs[t_n][t_seg * 8] = bPT[0];
            *(bf8v*)&Bs[t_n + 64][t_seg * 8] = bPT[1];
        } else {
#pragma unroll
            for (int i = 0; i < 4; ++i) {
                int n = s_f4 * 4 + i * 32;
                Bs[n + 0][s_kr] = f2bf(bP[i].x);
                Bs[n + 1][s_kr] = f2bf(bP[i].y);
                Bs[n + 2][s_kr] = f2bf(bP[i].z);
                Bs[n + 3][s_kr] = f2bf(bP[i].w);
            }
        }
        __syncthreads();

        if (kt + 32 < kchunk) { loadB(kt + 32); loadA(kt + 32); }

        bf8v af[4], bfv[4];
#pragma unroll
        for (int f = 0; f < 4; ++f) af[f] = *(const bf8v*)&As[wm + f * 16 + r16][kg * 8];
#pragma unroll
        for (int f = 0; f < 4; ++f) bfv[f] = *(const bf8v*)&Bs[wn + f * 16 + r16][kg * 8];
#pragma unroll
        for (int i = 0; i < 4; ++i)
#pragma unroll
            for (int j = 0; j < 4; ++j)
                acc[i][j] = __builtin_amdgcn_mfma_f32_16x16x32_bf16(af[i], bfv[j], acc[i][j], 0, 0, 0);
    }

    const int crow0 = m0 + wm + (lane >> 4) * 4;
#pragma unroll
    for (int i = 0; i < 4; ++i) {
#pragma unroll
        for (int j = 0; j < 4; ++j) {
            float* base = C + (size_t)(crow0 + i * 16) * DOUT + wn + j * 16 + r16;
            unsafeAtomicAdd(base + 0 * DOUT, acc[i][j][0]);
            unsafeAtomicAdd(base + 1 * DOUT, acc[i][j][1]);
            unsafeAtomicAdd(base + 2 * DOUT, acc[i][j][2]);
            unsafeAtomicAdd(base + 3 * DOUT, acc[i][j][3]);
        }
    }
}

// Three independent NN/BTF GEMMs co-scheduled in one flat grid:
//  bid < n0:        A0 @ B0T -> C0   (nx0 m-tiles x 8 splits)
//  bid < n0+n1:     A1 @ B1T -> C0
//  else:            A2 @ B2T -> C2
__global__ __launch_bounds__(256)
void gemm_triple_kernel(const float* __restrict__ A0, int lda0, const ushort* __restrict__ B0T, int ldb0, int kc0, int n0,
                        const float* __restrict__ A1, int lda1, const ushort* __restrict__ B1T, int ldb1, int kc1, int n1,
                        const float* __restrict__ A2, int lda2, const ushort* __restrict__ B2T, int ldb2, int kc2,
                        float* __restrict__ C0, float* __restrict__ C2) {
    __shared__ ushort As[128][40];
    __shared__ ushort Bs[128][40];
    int bid = blockIdx.x;
    if (bid < n0) {
        gemm_body<0, 1>(As, Bs, A0, lda0, nullptr, B0T, ldb0, C0, kc0, (bid & 7) * kc0, (bid >> 3) * 128);
    } else if (bid < n0 + n1) {
        int b = bid - n0;
        gemm_body<0, 1>(As, Bs, A1, lda1, nullptr, B1T, ldb1, C0, kc1, (b & 7) * kc1, (b >> 3) * 128);
    } else {
        int b = bid - n0 - n1;
        gemm_body<0, 1>(As, Bs, A2, lda2, nullptr, B2T, ldb2, C2, kc2, (b & 7) * kc2, (b >> 3) * 128);
    }
}

// Single GEMM (used for the dependent adj^T @ xns)
template<int TRANS, int BTF>
__global__ __launch_bounds__(256)
void gemm_single_kernel(const float* __restrict__ A, int lda,
                        const float* __restrict__ Bf, const ushort* __restrict__ bT, int ldb,
                        float* __restrict__ C, int kchunk) {
    __shared__ ushort As[128][40];
    __shared__ ushort Bs[128][40];
    gemm_body<TRANS, BTF>(As, Bs, A, lda, Bf, bT, ldb, C, kchunk, blockIdx.y * kchunk, blockIdx.x * 128);
}

// x_new = relu(xs + C1/rs) -> d_out;  xns = x_new/rs -> ws (fp32)
__global__ void epilogue1_kernel(const float* __restrict__ C1,
                                 const float* __restrict__ xs,
                                 const float* __restrict__ rs,
                                 float* __restrict__ outx,
                                 float* __restrict__ xns) {
    int idx = blockIdx.x * blockDim.x + threadIdx.x;
    if (idx >= NS * DOUT) return;
    int row = idx >> 7;
    float r = rs[row];
    float v = xs[idx] + C1[idx] / r;
    v = v > 0.f ? v : 0.f;
    outx[idx] = v;
    xns[idx] = v / r;
}

// y_new = relu(ys + C2/rt) -> d_out + NS*DOUT
__global__ void epilogue2_kernel(const float* __restrict__ C2,
                                 const float* __restrict__ ys,
                                 const float* __restrict__ rt,
                                 float* __restrict__ outy) {
    int idx = blockIdx.x * blockDim.x + threadIdx.x;
    if (idx >= NT * DOUT) return;
    int row = idx >> 7;
    float v = ys[idx] + C2[idx] / rt[row];
    v = v > 0.f ? v : 0.f;
    outy[idx] = v;
}

extern "C" void kernel_launch(void* const* d_in, const int* in_sizes, int n_in,
                              void* d_out, int out_size, void* d_ws, size_t ws_size,
                              hipStream_t stream) {
    const float* inp_s = (const float*)d_in[0];
    const float* inp_t = (const float*)d_in[1];
    const float* adj   = (const float*)d_in[2];
    const float* adj_s = (const float*)d_in[3];
    const float* adj_t = (const float*)d_in[4];
    const float* W     = (const float*)d_in[5];
    float* out = (float*)d_out;
    float* ws  = (float*)d_ws;

    float* rs  = ws + OFF_RS;
    float* rt  = ws + OFF_RT;
    float* C1  = ws + OFF_C1;
    float* C2  = ws + OFF_C2;
    float* xs  = ws + OFF_XS;
    float* ys  = ws + OFF_YS;
    float* xns = ws + OFF_XNS;
    ushort* xsT = (ushort*)(ws + OFF_XST);
    ushort* ysT = (ushort*)(ws + OFF_YST);

    // zero deg_s + deg_t + C1 + C2 (contiguous [0, OFF_XS))
    zero_kernel<<<1024, 256, 0, stream>>>(ws, OFF_XS / 4);

    // Degree pass, ordered for LLC residency in the GEMM phase:
    // stream adj_t (268 MB) FIRST so adj (134 MB) + adj_s (67 MB) stay resident.
    colsum_t_kernel<<<dim3(NT / 1024, NT / 64), 256, 0, stream>>>(adj_t, rt);
    adj_deg_kernel<<<dim3(NT / 1024, NS / 32), 256, 0, stream>>>(adj, rs, rt);
    rowsum_s_kernel<<<NS / 4, 256, 0, stream>>>(adj_s, rs);
    finish_deg_kernel<<<(NS + NT) / 256, 256, 0, stream>>>(rs);   // rs|rt contiguous

    // projections: xs = (inp_s@W)/rs (fp32) + xsT (bf16 transposed); same for ys
    proj_scale_kernel<<<NS / 64, 256, 0, stream>>>(inp_s, W, rs, xs, xsT, NS);
    proj_scale_kernel<<<NT / 64, 256, 0, stream>>>(inp_t, W, rt, ys, ysT, NT);

    // Phase A: all three independent GEMMs co-scheduled (1024 blocks = 4/CU):
    //   adj_s@xs -> C1 (256 blk), adj@ys -> C1 (256 blk), adj_t@ys -> C2 (512 blk).
    // Overlaps the cold adj_t HBM stream with the LLC-warm C1 GEMMs.
    gemm_triple_kernel<<<1024, 256, 0, stream>>>(
        adj_s, NS, xsT, NS, NS / 8, 256,
        adj,   NT, ysT, NT, NT / 8, 256,
        adj_t, NT, ysT, NT, NT / 8,
        C1, C2);
    epilogue1_kernel<<<(NS * DOUT) / 256, 256, 0, stream>>>(C1, xs, rs, out, xns);

    // Phase B: dependent adj^T @ xns -> C2 (adj LLC-warm from phase A)
    gemm_single_kernel<1, 0><<<dim3(NT / 128, 8), 256, 0, stream>>>(adj, NT, xns, nullptr, 0, C2, NS / 8);
    epilogue2_kernel<<<(NT * DOUT) / 256, 256, 0, stream>>>(C2, ys, rt, out + NS * DOUT);
}

// Round 14
// 325.946 us; speedup vs baseline: 1.2251x; 1.0827x over previous
//
#include <hip/hip_runtime.h>

#define NS 4096
#define NT 8192
#define DIN 256
#define DOUT 128

// float offsets into workspace
#define OFF_RS   0                       // deg_s then rs in place [NS]
#define OFF_RT   (NS)                    // deg_t then rt in place [NT]
#define OFF_C1   (OFF_RT + NT)
#define OFF_C2   (OFF_C1 + NS*DOUT)
#define OFF_XS   (OFF_C2 + NT*DOUT)
#define OFF_YS   (OFF_XS + NS*DOUT)
#define OFF_XNS  (OFF_YS + NT*DOUT)
#define OFF_XST  (OFF_XNS + NS*DOUT)               // bf16 [128][NS]
#define OFF_YST  (OFF_XST + (128*NS)/2)            // bf16 [128][NT]

typedef __attribute__((ext_vector_type(8))) short bf8v;
typedef __attribute__((ext_vector_type(4))) float f32x4;
typedef __attribute__((ext_vector_type(4))) unsigned short u16x4;

__device__ __forceinline__ ushort f2bf(float f) {
    // exact round-to-nearest-even fp32 -> bf16 (finite inputs only)
    unsigned x = __float_as_uint(f);
    unsigned r = (x + 0x7fffu + ((x >> 16) & 1u)) >> 16;
    return (ushort)r;
}

__global__ void zero_kernel(float* __restrict__ p, int n4) {
    int i = blockIdx.x * blockDim.x + threadIdx.x;
    int stride = gridDim.x * blockDim.x;
    float4* p4 = (float4*)p;
    float4 z = make_float4(0.f, 0.f, 0.f, 0.f);
    for (; i < n4; i += stride) p4[i] = z;
}

// All three degree reductions co-scheduled in one flat grid (3072 blocks).
// bids [0,1024):    adj_t col partials -> deg_t      (streams FIRST: cold 268 MB)
// bids [1024,2048): adj fused row+col -> deg_s,deg_t (stays LLC-warm for GEMMs)
// bids [2048,3072): adj_s row sums -> deg_s          (last: LLC-warm for GEMMs)
__global__ __launch_bounds__(256)
void deg_mega_kernel(const float* __restrict__ adj,
                     const float* __restrict__ adj_s,
                     const float* __restrict__ adj_t,
                     float* __restrict__ deg_s, float* __restrict__ deg_t) {
    const int tid = threadIdx.x;
    const int lane = tid & 63;
    const int bid = blockIdx.x;
    if (bid < 1024) {
        // colsum over adj_t: 64 rows per block
        const int c4 = (bid & 7) * 256 + tid;
        const int r0 = (bid >> 3) * 64;
        const float4* A4 = (const float4*)adj_t + (size_t)r0 * (NT / 4) + c4;
        float sx = 0.f, sy = 0.f, sz = 0.f, sw = 0.f;
#pragma unroll 8
        for (int r = 0; r < 64; ++r) {
            float4 v = A4[(size_t)r * (NT / 4)];
            sx += v.x; sy += v.y; sz += v.z; sw += v.w;
        }
        float* d = deg_t + c4 * 4;
        unsafeAtomicAdd(d + 0, sx);
        unsafeAtomicAdd(d + 1, sy);
        unsafeAtomicAdd(d + 2, sz);
        unsafeAtomicAdd(d + 3, sw);
    } else if (bid < 2048) {
        // fused row+col over adj: 32 rows per block
        const int b = bid - 1024;
        const int c4 = (b & 7) * 256 + tid;
        const int r0 = (b >> 3) * 32;
        const float4* A4 = (const float4*)adj + (size_t)r0 * (NT / 4) + c4;
        float sx = 0.f, sy = 0.f, sz = 0.f, sw = 0.f;
#pragma unroll 8
        for (int r = 0; r < 32; ++r) {
            float4 v = A4[(size_t)r * (NT / 4)];
            sx += v.x; sy += v.y; sz += v.z; sw += v.w;
            float rp = v.x + v.y + v.z + v.w;
#pragma unroll
            for (int off = 32; off > 0; off >>= 1) rp += __shfl_down(rp, off, 64);
            if (lane == 0) unsafeAtomicAdd(deg_s + r0 + r, rp);
        }
        float* d = deg_t + c4 * 4;
        unsafeAtomicAdd(d + 0, sx);
        unsafeAtomicAdd(d + 1, sy);
        unsafeAtomicAdd(d + 2, sz);
        unsafeAtomicAdd(d + 3, sw);
    } else {
        // row sums over adj_s: one wave per row
        const int b = bid - 2048;
        const int wid = tid >> 6;
        const int row = b * 4 + wid;
        const float4* p = (const float4*)(adj_s + (size_t)row * NS);
        float sum = 0.f;
#pragma unroll 8
        for (int c = lane; c < NS / 4; c += 64) { float4 v = p[c]; sum += v.x + v.y + v.z + v.w; }
#pragma unroll
        for (int off = 32; off > 0; off >>= 1) sum += __shfl_down(sum, off, 64);
        if (lane == 0) unsafeAtomicAdd(deg_s + row, sum);
    }
}

// deg -> sqrt(deg + 1), in place over rs|rt (contiguous NS+NT)
__global__ void finish_deg_kernel(float* __restrict__ deg) {
    int t = blockIdx.x * blockDim.x + threadIdx.x;
    deg[t] = sqrtf(deg[t] + 1.0f);
}

// Both projections in one launch: out[m,:] = (inp[m,:]@W)/rdeg[m] (fp32)
// plus outT[n][m] = bf16(out[m][n]).  bids [0,NS/64) -> s-side, rest -> t-side.
__global__ __launch_bounds__(256)
void proj_scale_kernel(const float* __restrict__ inp_s,
                       const float* __restrict__ inp_t,
                       const float* __restrict__ W,
                       const float* __restrict__ rs, const float* __restrict__ rt,
                       float* __restrict__ xs, float* __restrict__ ys,
                       ushort* __restrict__ xsT, ushort* __restrict__ ysT) {
    __shared__ float As[32][68];
    __shared__ float Bs[32][128];
    const int tid = threadIdx.x;

    const float* inp; const float* rdeg; float* outp; ushort* outT; int M; int m0;
    if (blockIdx.x < NS / 64) {
        inp = inp_s; rdeg = rs; outp = xs; outT = xsT; M = NS; m0 = blockIdx.x * 64;
    } else {
        int b = blockIdx.x - NS / 64;
        inp = inp_t; rdeg = rt; outp = ys; outT = ysT; M = NT; m0 = b * 64;
    }

    const int tx = tid & 15, ty = tid >> 4;
    const int arow = tid >> 3, acg = tid & 7;
    const int bk = tid >> 5, bng = tid & 31;

    float acc[4][8];
#pragma unroll
    for (int r = 0; r < 4; ++r)
#pragma unroll
        for (int c = 0; c < 8; ++c) acc[r][c] = 0.f;

    for (int kt = 0; kt < DIN; kt += 32) {
        const float* Ab = inp + (size_t)(m0 + arow) * DIN + kt + acg * 4;
        float4 a0 = *(const float4*)Ab;
        float4 a1 = *(const float4*)(Ab + (size_t)32 * DIN);
        const float* Bb = W + (size_t)(kt + bk) * DOUT + bng * 4;
        float4 b0 = *(const float4*)Bb;
        float4 b1 = *(const float4*)(Bb + 8 * DOUT);
        float4 b2 = *(const float4*)(Bb + 16 * DOUT);
        float4 b3 = *(const float4*)(Bb + 24 * DOUT);
        __syncthreads();
        As[acg * 4 + 0][arow] = a0.x;
        As[acg * 4 + 1][arow] = a0.y;
        As[acg * 4 + 2][arow] = a0.z;
        As[acg * 4 + 3][arow] = a0.w;
        As[acg * 4 + 0][arow + 32] = a1.x;
        As[acg * 4 + 1][arow + 32] = a1.y;
        As[acg * 4 + 2][arow + 32] = a1.z;
        As[acg * 4 + 3][arow + 32] = a1.w;
        *(float4*)&Bs[bk][bng * 4] = b0;
        *(float4*)&Bs[bk + 8][bng * 4] = b1;
        *(float4*)&Bs[bk + 16][bng * 4] = b2;
        *(float4*)&Bs[bk + 24][bng * 4] = b3;
        __syncthreads();
#pragma unroll
        for (int k = 0; k < 32; ++k) {
            float4 av = *(const float4*)&As[k][ty * 4];
            float4 bv0 = *(const float4*)&Bs[k][tx * 4];
            float4 bv1 = *(const float4*)&Bs[k][tx * 4 + 64];
            float a[4] = {av.x, av.y, av.z, av.w};
            float b[8] = {bv0.x, bv0.y, bv0.z, bv0.w, bv1.x, bv1.y, bv1.z, bv1.w};
#pragma unroll
            for (int r = 0; r < 4; ++r)
#pragma unroll
                for (int c = 0; c < 8; ++c) acc[r][c] = fmaf(a[r], b[c], acc[r][c]);
        }
    }
    float rds[4];
#pragma unroll
    for (int r = 0; r < 4; ++r) rds[r] = rdeg[m0 + ty * 4 + r];
#pragma unroll
    for (int r = 0; r < 4; ++r) {
        int row = m0 + ty * 4 + r;
        float* orow = outp + (size_t)row * DOUT;
#pragma unroll
        for (int c = 0; c < 8; ++c) acc[r][c] /= rds[r];
#pragma unroll
        for (int c = 0; c < 4; ++c) {
            orow[tx * 4 + c] = acc[r][c];
            orow[tx * 4 + 64 + c] = acc[r][4 + c];
        }
    }
#pragma unroll
    for (int c = 0; c < 8; ++c) {
        int col = tx * 4 + (c & 3) + (c >> 2) * 64;
        u16x4 w;
#pragma unroll
        for (int r = 0; r < 4; ++r) w[r] = f2bf(acc[r][c]);
        *(u16x4*)&outT[(size_t)col * M + m0 + ty * 4] = w;
    }
}

// One 128x128 output tile over one K-chunk; the r8-proven GEMM body.
// TRANS=0: A[m][k] pitch lda.  TRANS=1: op(A)=A^T with A[k][m] pitch lda.
// BTF=1: B bf16 transposed bT[n][k] pitch ldb.  BTF=0: B fp32 row-major [k][128].
template<int TRANS, int BTF>
__device__ __forceinline__
void gemm_body(ushort (*As)[40], ushort (*Bs)[40],
               const float* __restrict__ A, int lda,
               const float* __restrict__ Bf,
               const ushort* __restrict__ bT, int ldb,
               float* __restrict__ C, int kchunk, int k0, int m0) {
    const int tid = threadIdx.x;
    const int lane = tid & 63, wid = tid >> 6;
    const int wm = (wid >> 1) * 64, wn = (wid & 1) * 64;
    const int r16 = lane & 15, kg = lane >> 4;

    const int s_kr = tid >> 3, s_f4 = tid & 7;   // fp32-B / TRANS-A staging map
    const int a_r = tid >> 1, a_seg = tid & 1;   // NN-A staging map
    const int t_n = tid >> 2, t_seg = tid & 3;   // bf16-T B staging map

    f32x4 acc[4][4];
#pragma unroll
    for (int i = 0; i < 4; ++i)
#pragma unroll
        for (int j = 0; j < 4; ++j) acc[i][j] = (f32x4)(0.f);

    float4 aP[4], bP[4];
    bf8v bPT[2];

    auto loadB = [&](int ktb) {
        if (BTF) {
            const ushort* Tb = bT + (size_t)t_n * ldb + k0 + ktb + t_seg * 8;
            bPT[0] = *(const bf8v*)Tb;
            bPT[1] = *(const bf8v*)(Tb + (size_t)64 * ldb);
        } else {
            const float* Bb = Bf + (size_t)(k0 + ktb + s_kr) * DOUT + s_f4 * 4;
#pragma unroll
            for (int i = 0; i < 4; ++i) bP[i] = *(const float4*)(Bb + i * 32);
        }
    };
    auto loadA = [&](int ktb) {
        if (TRANS) {
            const float* Ab = A + (size_t)(k0 + ktb + s_kr) * lda + m0 + s_f4 * 4;
#pragma unroll
            for (int i = 0; i < 4; ++i) aP[i] = *(const float4*)(Ab + i * 32);
        } else {
            const float* Ab = A + (size_t)(m0 + a_r) * lda + k0 + ktb + a_seg * 16;
#pragma unroll
            for (int i = 0; i < 4; ++i) aP[i] = *(const float4*)(Ab + i * 4);
        }
    };

    loadB(0); loadA(0);

    for (int kt = 0; kt < kchunk; kt += 32) {
        __syncthreads();
        if (TRANS) {
#pragma unroll
            for (int i = 0; i < 4; ++i) {
                int m = s_f4 * 4 + i * 32;
                As[m + 0][s_kr] = f2bf(aP[i].x);
                As[m + 1][s_kr] = f2bf(aP[i].y);
                As[m + 2][s_kr] = f2bf(aP[i].z);
                As[m + 3][s_kr] = f2bf(aP[i].w);
            }
        } else {
            bf8v w0, w1;
            w0[0] = (short)f2bf(aP[0].x); w0[1] = (short)f2bf(aP[0].y);
            w0[2] = (short)f2bf(aP[0].z); w0[3] = (short)f2bf(aP[0].w);
            w0[4] = (short)f2bf(aP[1].x); w0[5] = (short)f2bf(aP[1].y);
            w0[6] = (short)f2bf(aP[1].z); w0[7] = (short)f2bf(aP[1].w);
            w1[0] = (short)f2bf(aP[2].x); w1[1] = (short)f2bf(aP[2].y);
            w1[2] = (short)f2bf(aP[2].z); w1[3] = (short)f2bf(aP[2].w);
            w1[4] = (short)f2bf(aP[3].x); w1[5] = (short)f2bf(aP[3].y);
            w1[6] = (short)f2bf(aP[3].z); w1[7] = (short)f2bf(aP[3].w);
            *(bf8v*)&As[a_r][a_seg * 16] = w0;
            *(bf8v*)&As[a_r][a_seg * 16 + 8] = w1;
        }
        if (BTF) {
            *(bf8v*)&Bs[t_n][t_seg * 8] = bPT[0];
            *(bf8v*)&Bs[t_n + 64][t_seg * 8] = bPT[1];
        } else {
#pragma unroll
            for (int i = 0; i < 4; ++i) {
                int n = s_f4 * 4 + i * 32;
                Bs[n + 0][s_kr] = f2bf(bP[i].x);
                Bs[n + 1][s_kr] = f2bf(bP[i].y);
                Bs[n + 2][s_kr] = f2bf(bP[i].z);
                Bs[n + 3][s_kr] = f2bf(bP[i].w);
            }
        }
        __syncthreads();

        if (kt + 32 < kchunk) { loadB(kt + 32); loadA(kt + 32); }

        bf8v af[4], bfv[4];
#pragma unroll
        for (int f = 0; f < 4; ++f) af[f] = *(const bf8v*)&As[wm + f * 16 + r16][kg * 8];
#pragma unroll
        for (int f = 0; f < 4; ++f) bfv[f] = *(const bf8v*)&Bs[wn + f * 16 + r16][kg * 8];
#pragma unroll
        for (int i = 0; i < 4; ++i)
#pragma unroll
            for (int j = 0; j < 4; ++j)
                acc[i][j] = __builtin_amdgcn_mfma_f32_16x16x32_bf16(af[i], bfv[j], acc[i][j], 0, 0, 0);
    }

    const int crow0 = m0 + wm + (lane >> 4) * 4;
#pragma unroll
    for (int i = 0; i < 4; ++i) {
#pragma unroll
        for (int j = 0; j < 4; ++j) {
            float* base = C + (size_t)(crow0 + i * 16) * DOUT + wn + j * 16 + r16;
            unsafeAtomicAdd(base + 0 * DOUT, acc[i][j][0]);
            unsafeAtomicAdd(base + 1 * DOUT, acc[i][j][1]);
            unsafeAtomicAdd(base + 2 * DOUT, acc[i][j][2]);
            unsafeAtomicAdd(base + 3 * DOUT, acc[i][j][3]);
        }
    }
}

// Three independent NN/BTF GEMMs co-scheduled in one flat grid.
__global__ __launch_bounds__(256)
void gemm_triple_kernel(const float* __restrict__ A0, int lda0, const ushort* __restrict__ B0T, int ldb0, int kc0, int n0,
                        const float* __restrict__ A1, int lda1, const ushort* __restrict__ B1T, int ldb1, int kc1, int n1,
                        const float* __restrict__ A2, int lda2, const ushort* __restrict__ B2T, int ldb2, int kc2,
                        float* __restrict__ C0, float* __restrict__ C2) {
    __shared__ ushort As[128][40];
    __shared__ ushort Bs[128][40];
    int bid = blockIdx.x;
    if (bid < n0) {
        gemm_body<0, 1>(As, Bs, A0, lda0, nullptr, B0T, ldb0, C0, kc0, (bid & 7) * kc0, (bid >> 3) * 128);
    } else if (bid < n0 + n1) {
        int b = bid - n0;
        gemm_body<0, 1>(As, Bs, A1, lda1, nullptr, B1T, ldb1, C0, kc1, (b & 7) * kc1, (b >> 3) * 128);
    } else {
        int b = bid - n0 - n1;
        gemm_body<0, 1>(As, Bs, A2, lda2, nullptr, B2T, ldb2, C2, kc2, (b & 7) * kc2, (b >> 3) * 128);
    }
}

// Single GEMM (used for the dependent adj^T @ xns)
template<int TRANS, int BTF>
__global__ __launch_bounds__(256)
void gemm_single_kernel(const float* __restrict__ A, int lda,
                        const float* __restrict__ Bf, const ushort* __restrict__ bT, int ldb,
                        float* __restrict__ C, int kchunk) {
    __shared__ ushort As[128][40];
    __shared__ ushort Bs[128][40];
    gemm_body<TRANS, BTF>(As, Bs, A, lda, Bf, bT, ldb, C, kchunk, blockIdx.y * kchunk, blockIdx.x * 128);
}

// x_new = relu(xs + C1/rs) -> d_out;  xns = x_new/rs -> ws (fp32)
__global__ void epilogue1_kernel(const float* __restrict__ C1,
                                 const float* __restrict__ xs,
                                 const float* __restrict__ rs,
                                 float* __restrict__ outx,
                                 float* __restrict__ xns) {
    int idx = blockIdx.x * blockDim.x + threadIdx.x;
    if (idx >= NS * DOUT) return;
    int row = idx >> 7;
    float r = rs[row];
    float v = xs[idx] + C1[idx] / r;
    v = v > 0.f ? v : 0.f;
    outx[idx] = v;
    xns[idx] = v / r;
}

// y_new = relu(ys + C2/rt) -> d_out + NS*DOUT
__global__ void epilogue2_kernel(const float* __restrict__ C2,
                                 const float* __restrict__ ys,
                                 const float* __restrict__ rt,
                                 float* __restrict__ outy) {
    int idx = blockIdx.x * blockDim.x + threadIdx.x;
    if (idx >= NT * DOUT) return;
    int row = idx >> 7;
    float v = ys[idx] + C2[idx] / rt[row];
    v = v > 0.f ? v : 0.f;
    outy[idx] = v;
}

extern "C" void kernel_launch(void* const* d_in, const int* in_sizes, int n_in,
                              void* d_out, int out_size, void* d_ws, size_t ws_size,
                              hipStream_t stream) {
    const float* inp_s = (const float*)d_in[0];
    const float* inp_t = (const float*)d_in[1];
    const float* adj   = (const float*)d_in[2];
    const float* adj_s = (const float*)d_in[3];
    const float* adj_t = (const float*)d_in[4];
    const float* W     = (const float*)d_in[5];
    float* out = (float*)d_out;
    float* ws  = (float*)d_ws;

    float* rs  = ws + OFF_RS;
    float* rt  = ws + OFF_RT;
    float* C1  = ws + OFF_C1;
    float* C2  = ws + OFF_C2;
    float* xs  = ws + OFF_XS;
    float* ys  = ws + OFF_YS;
    float* xns = ws + OFF_XNS;
    ushort* xsT = (ushort*)(ws + OFF_XST);
    ushort* ysT = (ushort*)(ws + OFF_YST);

    // zero deg_s + deg_t + C1 + C2 (contiguous [0, OFF_XS))
    zero_kernel<<<1024, 256, 0, stream>>>(ws, OFF_XS / 4);

    // Degree pass: all three reductions co-scheduled in one launch.
    // Low bids stream adj_t first; adj + adj_s read last -> LLC-warm for GEMMs.
    deg_mega_kernel<<<3072, 256, 0, stream>>>(adj, adj_s, adj_t, rs, rt);
    finish_deg_kernel<<<(NS + NT) / 256, 256, 0, stream>>>(rs);   // rs|rt contiguous

    // Both projections in one launch: xs/xsT and ys/ysT
    proj_scale_kernel<<<(NS + NT) / 64, 256, 0, stream>>>(inp_s, inp_t, W, rs, rt, xs, ys, xsT, ysT);

    // Phase A: three independent GEMMs co-scheduled (1024 blocks = 4/CU):
    //   adj_s@xs -> C1 (256 blk), adj@ys -> C1 (256 blk), adj_t@ys -> C2 (512 blk).
    gemm_triple_kernel<<<1024, 256, 0, stream>>>(
        adj_s, NS, xsT, NS, NS / 8, 256,
        adj,   NT, ysT, NT, NT / 8, 256,
        adj_t, NT, ysT, NT, NT / 8,
        C1, C2);
    epilogue1_kernel<<<(NS * DOUT) / 256, 256, 0, stream>>>(C1, xs, rs, out, xns);

    // Phase B: dependent adj^T @ xns -> C2 (adj LLC-warm from phase A)
    gemm_single_kernel<1, 0><<<dim3(NT / 128, 8), 256, 0, stream>>>(adj, NT, xns, nullptr, 0, C2, NS / 8);
    epilogue2_kernel<<<(NT * DOUT) / 256, 256, 0, stream>>>(C2, ys, rt, out + NS * DOUT);
}